// Round 13
// baseline (194.426 us; speedup 1.0000x reference)
//
#include <hip/hip_runtime.h>
#include <hip/hip_bf16.h>

typedef short bf16x8 __attribute__((ext_vector_type(8)));
typedef float f32x4  __attribute__((ext_vector_type(4)));

typedef __attribute__((address_space(3))) void lds_t;
typedef __attribute__((address_space(1))) void gbl_t;

#define MFMA16(a,b,c) __builtin_amdgcn_mfma_f32_16x16x32_bf16((a),(b),(c),0,0,0)

__device__ __forceinline__ unsigned short f2bf(float f) {
    __hip_bfloat16 h = __float2bfloat16(f);
    return __builtin_bit_cast(unsigned short, h);
}
__device__ __forceinline__ float bf2f(unsigned short u) {
    __hip_bfloat16 h = __builtin_bit_cast(__hip_bfloat16, u);
    return __bfloat162float(h);
}

// f32 [R][1024] -> bf16 hi-only compact [R][1024].  float4 vectorized.
__global__ void prep_hi_rows(const float* __restrict__ src,
                             unsigned short* __restrict__ dst, int total4) {
    for (int idx = blockIdx.x * blockDim.x + threadIdx.x; idx < total4;
         idx += gridDim.x * blockDim.x) {
        int base = idx * 4;
        float4 v = *reinterpret_cast<const float4*>(src + base);
        ushort4 hi;
        hi.x = f2bf(v.x);
        hi.y = f2bf(v.y);
        hi.z = f2bf(v.z);
        hi.w = f2bf(v.w);
        *reinterpret_cast<ushort4*>(dst + base) = hi;
    }
}

// w_qkv [3072][1024], einops row permute (out row n = which*1024+h*64+d reads
// src row d*48+which*16+h) -> bf16 hi-only compact [3072][1024].
__global__ void prep_hi_wqkv(const float* __restrict__ w,
                             unsigned short* __restrict__ dst) {
    for (int idx = blockIdx.x * blockDim.x + threadIdx.x; idx < 3072 * 256;
         idx += gridDim.x * blockDim.x) {
        int base = idx * 4;
        int n = base >> 10, c = base & 1023;
        int d = n & 63, which = n >> 10, h = (n >> 6) & 15;
        int srow = d * 48 + which * 16 + h;
        float4 v = *reinterpret_cast<const float4*>(w + (size_t)srow * 1024 + c);
        ushort4 hi;
        hi.x = f2bf(v.x);
        hi.y = f2bf(v.y);
        hi.z = f2bf(v.z);
        hi.w = f2bf(v.w);
        *reinterpret_cast<ushort4*>(dst + (size_t)n * 1024 + c) = hi;
    }
}

// ============================================================================
// 256x256 hi-only bf16 GEMM for QKV (exact R10 structure — R12's fused-V^T
// epilogue regressed 33->62us via scattered 8B/2KB-stride stores; reverted).
// grid (12,16)=192 blocks, 512 thr / 8 waves (2Mx4N), wave tile 128x64,
// acc[8][4], 4-slot ring, counted vmcnt(4), chunk-XOR swizzle (0 conflicts).
// ============================================================================
__global__ __launch_bounds__(512, 2) void gemm256_hi(
    const unsigned short* __restrict__ A, const unsigned short* __restrict__ B,
    unsigned short* __restrict__ outQ, unsigned short* __restrict__ outK,
    unsigned short* __restrict__ outV) {
    __shared__ unsigned short lds[65536];  // A ring [0,32768), B ring [32768,65536)
    const int tid = threadIdx.x;
    const int wid = tid >> 6, lane = tid & 63;
    const int lrow = lane & 15, lgrp = lane >> 4;
    const int wr = wid >> 2, wc = wid & 3;
    const int mtile = blockIdx.y * 256, ntile = blockIdx.x * 256;

    const int csw = lgrp ^ ((lrow >> 1) & 3);
    const int aoff = (wr * 128 + lrow) * 32 + csw * 8;
    const int boff = 32768 + (wc * 64 + lrow) * 32 + csw * 8;

    const int sreg = wid * 2;
    const int srow0 = sreg * 16 + (lane >> 2);
    const int srow1 = (sreg + 1) * 16 + (lane >> 2);
    const int schunk = (lane & 3) ^ ((lane >> 3) & 3);
    const int sdst0 = sreg * 512;

    f32x4 acc[8][4];
#pragma unroll
    for (int i = 0; i < 8; ++i)
#pragma unroll
        for (int j = 0; j < 4; ++j) {
            f32x4 z = {0.f, 0.f, 0.f, 0.f};
            acc[i][j] = z;
        }

#pragma unroll
    for (int s0 = 0; s0 < 2; ++s0) {
        const int kb = s0 * 32;
        __builtin_amdgcn_global_load_lds(
            (const gbl_t*)(A + (size_t)(mtile + srow0) * 1024 + kb + schunk * 8),
            (lds_t*)(lds + s0 * 8192 + sdst0), 16, 0, 0);
        __builtin_amdgcn_global_load_lds(
            (const gbl_t*)(A + (size_t)(mtile + srow1) * 1024 + kb + schunk * 8),
            (lds_t*)(lds + s0 * 8192 + sdst0 + 512), 16, 0, 0);
        __builtin_amdgcn_global_load_lds(
            (const gbl_t*)(B + (size_t)(ntile + srow0) * 1024 + kb + schunk * 8),
            (lds_t*)(lds + 32768 + s0 * 8192 + sdst0), 16, 0, 0);
        __builtin_amdgcn_global_load_lds(
            (const gbl_t*)(B + (size_t)(ntile + srow1) * 1024 + kb + schunk * 8),
            (lds_t*)(lds + 32768 + s0 * 8192 + sdst0 + 512), 16, 0, 0);
    }
    asm volatile("s_waitcnt vmcnt(4)" ::: "memory");
    __syncthreads();

    for (int s = 0; s < 32; ++s) {
        const int sa = s & 3;
        const unsigned short* sbase = lds + sa * 8192;

        bf16x8 af[8];
#pragma unroll
        for (int i = 0; i < 8; ++i)
            af[i] = *reinterpret_cast<const bf16x8*>(sbase + aoff + i * 512);
        bf16x8 b0 = *reinterpret_cast<const bf16x8*>(sbase + boff);
        bf16x8 b1 = *reinterpret_cast<const bf16x8*>(sbase + boff + 512);

        if (s <= 29) {
            const int kb2 = (s + 2) * 32;
            const int s2 = (s + 2) & 3;
            __builtin_amdgcn_global_load_lds(
                (const gbl_t*)(A + (size_t)(mtile + srow0) * 1024 + kb2 + schunk * 8),
                (lds_t*)(lds + s2 * 8192 + sdst0), 16, 0, 0);
            __builtin_amdgcn_global_load_lds(
                (const gbl_t*)(A + (size_t)(mtile + srow1) * 1024 + kb2 + schunk * 8),
                (lds_t*)(lds + s2 * 8192 + sdst0 + 512), 16, 0, 0);
        }
        __builtin_amdgcn_s_setprio(1);
#pragma unroll
        for (int i = 0; i < 8; ++i) {
            acc[i][0] = MFMA16(af[i], b0, acc[i][0]);
            acc[i][1] = MFMA16(af[i], b1, acc[i][1]);
        }
        __builtin_amdgcn_s_setprio(0);

        bf16x8 b2 = *reinterpret_cast<const bf16x8*>(sbase + boff + 1024);
        bf16x8 b3 = *reinterpret_cast<const bf16x8*>(sbase + boff + 1536);
        if (s <= 29) {
            const int kb2 = (s + 2) * 32;
            const int s2 = (s + 2) & 3;
            __builtin_amdgcn_global_load_lds(
                (const gbl_t*)(B + (size_t)(ntile + srow0) * 1024 + kb2 + schunk * 8),
                (lds_t*)(lds + 32768 + s2 * 8192 + sdst0), 16, 0, 0);
            __builtin_amdgcn_global_load_lds(
                (const gbl_t*)(B + (size_t)(ntile + srow1) * 1024 + kb2 + schunk * 8),
                (lds_t*)(lds + 32768 + s2 * 8192 + sdst0 + 512), 16, 0, 0);
        }
        __builtin_amdgcn_s_setprio(1);
#pragma unroll
        for (int i = 0; i < 8; ++i) {
            acc[i][2] = MFMA16(af[i], b2, acc[i][2]);
            acc[i][3] = MFMA16(af[i], b3, acc[i][3]);
        }
        __builtin_amdgcn_s_setprio(0);

        if (s < 31) {
            if (s <= 29)
                asm volatile("s_waitcnt vmcnt(4)" ::: "memory");
            else
                asm volatile("s_waitcnt vmcnt(0)" ::: "memory");
            __syncthreads();
        }
    }

#pragma unroll
    for (int i = 0; i < 8; ++i) {
#pragma unroll
        for (int j = 0; j < 4; ++j) {
#pragma unroll
            for (int r = 0; r < 4; ++r) {
                float v = acc[i][j][r];
                int m = mtile + wr * 128 + i * 16 + lgrp * 4 + r;
                int n = ntile + wc * 64 + j * 16 + lrow;
                int which = n >> 10;
                int hh = (n >> 6) & 15;
                int d = n & 63;
                int b = m >> 10, t = m & 1023;
                unsigned short* dstp =
                    (which == 0) ? outQ : ((which == 1) ? outK : outV);
                dstp[((size_t)((b << 4) + hh) * 1024 + t) * 64 + d] = f2bf(v);
            }
        }
    }
}

// ============================================================================
// Out-projection GEMM v4 (R9, unchanged): hi-only bf16, K=1024, 64x128 tile,
// 512 blocks, 4-slot ring, counted vmcnt(3), XCD swizzle, 0 conflicts.
// ============================================================================
__global__ __launch_bounds__(256, 3) void gemm_out_v4(
    const unsigned short* __restrict__ A, const unsigned short* __restrict__ B,
    float* __restrict__ outF) {
    __shared__ unsigned short As[4][64 * 32];   // 16 KB ring
    __shared__ unsigned short Bs[4][128 * 32];  // 32 KB ring
    const int tid = threadIdx.x;
    const int wid = tid >> 6, lane = tid & 63;
    const int lrow = lane & 15, lgrp = lane >> 4;
    const int wr = wid >> 1, wc = wid & 1;
    const int h = blockIdx.x;
    const int xcd = h & 7, within = h >> 3;
    const int mtile = (xcd * 8 + (within & 7)) * 64;
    const int ntile = (within >> 3) * 128;

    const int csw = lgrp ^ ((lrow >> 1) & 3);
    const int aoff = (wr * 32 + lrow) * 32 + csw * 8;  // + i*512
    const int boff = (wc * 64 + lrow) * 32 + csw * 8;  // + j*512

    const int srow = tid >> 2;                        // 0..63
    const int schunk = (tid & 3) ^ ((tid >> 3) & 3);  // inverse-swizzled src
    const unsigned short* Arow = A + (size_t)(mtile + srow) * 1024 + schunk * 8;
    const unsigned short* Brow0 = B + (size_t)(ntile + srow) * 1024 + schunk * 8;
    const unsigned short* Brow1 =
        B + (size_t)(ntile + 64 + srow) * 1024 + schunk * 8;

    f32x4 acc[2][4];
#pragma unroll
    for (int i = 0; i < 2; ++i)
#pragma unroll
        for (int j = 0; j < 4; ++j) {
            f32x4 z = {0.f, 0.f, 0.f, 0.f};
            acc[i][j] = z;
        }

#pragma unroll
    for (int s0 = 0; s0 < 2; ++s0) {
        const int kb = s0 * 32;
        __builtin_amdgcn_global_load_lds((const gbl_t*)(Arow + kb),
                                         (lds_t*)(&As[s0][0] + tid * 8), 16, 0,
                                         0);
        __builtin_amdgcn_global_load_lds((const gbl_t*)(Brow0 + kb),
                                         (lds_t*)(&Bs[s0][0] + tid * 8), 16, 0,
                                         0);
        __builtin_amdgcn_global_load_lds((const gbl_t*)(Brow1 + kb),
                                         (lds_t*)(&Bs[s0][0] + 2048 + tid * 8),
                                         16, 0, 0);
    }
    asm volatile("s_waitcnt vmcnt(3)" ::: "memory");  // slot 0 landed
    __syncthreads();

    for (int s = 0; s < 32; ++s) {
        const int sa = s & 3;
        if (s <= 29) {
            const int kb = (s + 2) * 32;
            const int s2 = (s + 2) & 3;
            __builtin_amdgcn_global_load_lds((const gbl_t*)(Arow + kb),
                                             (lds_t*)(&As[s2][0] + tid * 8), 16,
                                             0, 0);
            __builtin_amdgcn_global_load_lds((const gbl_t*)(Brow0 + kb),
                                             (lds_t*)(&Bs[s2][0] + tid * 8), 16,
                                             0, 0);
            __builtin_amdgcn_global_load_lds(
                (const gbl_t*)(Brow1 + kb),
                (lds_t*)(&Bs[s2][0] + 2048 + tid * 8), 16, 0, 0);
        }
        bf16x8 af[2], bfv[4];
#pragma unroll
        for (int i = 0; i < 2; ++i)
            af[i] = *reinterpret_cast<const bf16x8*>(&As[sa][0] + aoff + i * 512);
#pragma unroll
        for (int j = 0; j < 4; ++j)
            bfv[j] =
                *reinterpret_cast<const bf16x8*>(&Bs[sa][0] + boff + j * 512);
        __builtin_amdgcn_s_setprio(1);
#pragma unroll
        for (int i = 0; i < 2; ++i)
#pragma unroll
            for (int j = 0; j < 4; ++j)
                acc[i][j] = MFMA16(af[i], bfv[j], acc[i][j]);
        __builtin_amdgcn_s_setprio(0);
        if (s < 31) {
            if (s <= 29)
                asm volatile("s_waitcnt vmcnt(3)" ::: "memory");
            else
                asm volatile("s_waitcnt vmcnt(0)" ::: "memory");
            __syncthreads();
        }
    }

#pragma unroll
    for (int i = 0; i < 2; ++i)
#pragma unroll
        for (int j = 0; j < 4; ++j)
#pragma unroll
            for (int r = 0; r < 4; ++r) {
                int m = mtile + wr * 32 + i * 16 + lgrp * 4 + r;
                int n = ntile + wc * 64 + j * 16 + lrow;
                outF[(size_t)m * 1024 + n] = acc[i][j][r];
            }
}

// V [bh][1024][64] -> V^T [bh][64][1024], LDS-tiled, coalesced both sides.
__global__ __launch_bounds__(256) void transpose_v(
    const unsigned short* __restrict__ Vb, unsigned short* __restrict__ Vtg) {
    __shared__ unsigned short L[64][72];
    const int tt = blockIdx.x, bh = blockIdx.y;
    const int tid = threadIdx.x;
#pragma unroll
    for (int e = 0; e < 2; ++e) {
        int chunk = e * 256 + tid;
        int r = chunk >> 3, c = (chunk & 7) * 8;
        uint4 v = *reinterpret_cast<const uint4*>(
            Vb + ((size_t)bh * 1024 + tt * 64 + r) * 64 + c);
        *reinterpret_cast<uint4*>(&L[r][c]) = v;
    }
    __syncthreads();
#pragma unroll
    for (int e = 0; e < 2; ++e) {
        int chunk = e * 256 + tid;
        int d = chunk >> 3, t0 = (chunk & 7) * 8;
        unsigned short tmp[8];
#pragma unroll
        for (int u = 0; u < 8; ++u) tmp[u] = L[t0 + u][d];
        *reinterpret_cast<uint4*>(Vtg + ((size_t)bh * 64 + d) * 1024 + tt * 64 +
                                  t0) = *reinterpret_cast<const uint4*>(tmp);
    }
}

// ============================================================================
// Flash attention v3 (R13): NO K/V LDS staging — K/V^T per (b,h) is 256KB,
// L2-resident (8 q-blocks share each bh; 2 co-resident blocks/CU share the
// same 16KB tile pair -> L1-fit).  Catalog mistake #7: staging L2-fit data is
// pure overhead.  Fragments load DIRECTLY from global (both-sides swizzle
// cancels -> identical data), bias strip (1151 floats) staged once ->
// ZERO barriers in the main loop; Ps is per-wave (lgkmcnt-only).  Per-wave
// math byte-identical to R10 (swapped QK^T, exp2 softmax, defer-max, cvt_pk).
// QBLK=128, 8 waves, grid (8,64).  LDS 21KB.
// ============================================================================
__global__ __launch_bounds__(512) void attn_kernel(
    const unsigned short* __restrict__ Qb, const unsigned short* __restrict__ Kb,
    const unsigned short* __restrict__ Vtg, const float* __restrict__ rel_bias,
    unsigned short* __restrict__ A3) {
    const int qt = blockIdx.x;  // 0..7 (128 q-rows each)
    const int bh = blockIdx.y;  // 0..63
    const int b = bh >> 4, h = bh & 15;
    const int tid = threadIdx.x;
    const int w = tid >> 6, lane = tid & 63;  // w in 0..7
    const int lrow = lane & 15, lgrp = lane >> 4;
    const float LOG2E = 1.4426950408889634f;
    const float SCALE2 = 0.125f * 1.4426950408889634f;
    const float THR = 11.5f;  // ~8 nats in exp2 units

    __shared__ unsigned short Ps[8][16 * 64];  // 16 KB, per-wave
    __shared__ float BiasF[1152];              // 4.5 KB, staged once

    const unsigned short* Ktile = Kb + (size_t)bh * 1024 * 64;
    const unsigned short* Vtile = Vtg + (size_t)bh * 64 * 1024;

    const unsigned short* Qp =
        Qb + ((size_t)bh * 1024 + qt * 128 + w * 16 + lrow) * 64;
    bf16x8 qa0 = *reinterpret_cast<const bf16x8*>(Qp + lgrp * 8);
    bf16x8 qa1 = *reinterpret_cast<const bf16x8*>(Qp + 32 + lgrp * 8);

    float m_run = -3.0e38f;
    float l_run = 0.f;
    f32x4 o_acc[4];
#pragma unroll
    for (int n = 0; n < 4; n++) {
        f32x4 z = {0.f, 0.f, 0.f, 0.f};
        o_acc[n] = z;
    }

    // full-range bias: BiasF[t] covers idx = j - i + 127 (j in [0,1024),
    // i = qt*128 + il).  rowi = t + 896 - qt*128, provably in [0,2046].
    {
        const int rbase = 896 - qt * 128;
        for (int t = tid; t < 1151; t += 512)
            BiasF[t] = rel_bias[(size_t)(t + rbase) * 16 + h] * LOG2E;
        __syncthreads();  // the only block-wide barrier
    }

    // Bias index for (f, r): bbase + f*16 + r = (j0 + jl) - il + 127
    const int bbase = lgrp * 4 + 127 - w * 16 - lrow;

    for (int kv = 0; kv < 16; ++kv) {
        const int j0 = kv * 64;

        // ---- S^T = K Q^T: K fragments direct from global (L1/L2-hit) ----
        f32x4 s[4];
        __builtin_amdgcn_s_setprio(1);
#pragma unroll
        for (int f = 0; f < 4; ++f) {
            const unsigned short* krp =
                Ktile + (size_t)(j0 + f * 16 + lrow) * 64 + lgrp * 8;
            bf16x8 kb0 = *reinterpret_cast<const bf16x8*>(krp);
            bf16x8 kb1 = *reinterpret_cast<const bf16x8*>(krp + 32);
            f32x4 z = {0.f, 0.f, 0.f, 0.f};
            z = MFMA16(kb0, qa0, z);
            z = MFMA16(kb1, qa1, z);
            s[f] = z;
        }
        __builtin_amdgcn_s_setprio(0);

        // ---- softmax, row-local (exp2 domain) ----
        float x[4][4];
        float pm = -3.0e38f;
#pragma unroll
        for (int f = 0; f < 4; ++f)
#pragma unroll
            for (int r = 0; r < 4; ++r) {
                float xv = s[f][r] * SCALE2 + BiasF[j0 + bbase + f * 16 + r];
                x[f][r] = xv;
                pm = fmaxf(pm, xv);
            }
        pm = fmaxf(pm, __shfl_xor(pm, 16));
        pm = fmaxf(pm, __shfl_xor(pm, 32));

        if (!__all(pm - m_run <= THR)) {
            float mnew = fmaxf(m_run, pm);
            float corr = __builtin_amdgcn_exp2f(m_run - mnew);
            m_run = mnew;
            l_run *= corr;
            float cb[4];
#pragma unroll
            for (int r = 0; r < 4; ++r) cb[r] = __shfl(corr, lgrp * 4 + r);
#pragma unroll
            for (int n = 0; n < 4; n++)
#pragma unroll
                for (int r = 0; r < 4; r++) o_acc[n][r] *= cb[r];
        }

        float su = 0.f;
#pragma unroll
        for (int f = 0; f < 4; ++f)
#pragma unroll
            for (int r = 0; r < 4; ++r) {
                float pv = __builtin_amdgcn_exp2f(x[f][r] - m_run);
                x[f][r] = pv;
                su += pv;
            }
        l_run += su;

        // ---- P -> Ps (per-wave, swizzled; no cross-wave sync needed) ----
#pragma unroll
        for (int f = 0; f < 4; ++f) {
            unsigned int plo, phi;
            asm("v_cvt_pk_bf16_f32 %0, %1, %2"
                : "=v"(plo)
                : "v"(x[f][0]), "v"(x[f][1]));
            asm("v_cvt_pk_bf16_f32 %0, %1, %2"
                : "=v"(phi)
                : "v"(x[f][2]), "v"(x[f][3]));
            const int chunk = (f * 2 + (lgrp >> 1)) ^ (lrow & 7);
            uint2 pw;
            pw.x = plo;
            pw.y = phi;
            *reinterpret_cast<uint2*>(
                &Ps[w][lrow * 64 + chunk * 8 + (lgrp & 1) * 4]) = pw;
        }

        // ---- O += P V: V^T fragments direct from global ----
        __builtin_amdgcn_s_setprio(1);
#pragma unroll
        for (int jc = 0; jc < 2; ++jc) {
            int pc = ((4 * jc + lgrp) ^ (lrow & 7)) * 8;
            bf16x8 pa =
                *reinterpret_cast<const bf16x8*>(&Ps[w][0] + lrow * 64 + pc);
#pragma unroll
            for (int n = 0; n < 4; n++) {
                const unsigned short* vrp = Vtile +
                                            (size_t)(n * 16 + lrow) * 1024 + j0 +
                                            jc * 32 + lgrp * 8;
                bf16x8 vb = *reinterpret_cast<const bf16x8*>(vrp);
                o_acc[n] = MFMA16(pa, vb, o_acc[n]);
            }
        }
        __builtin_amdgcn_s_setprio(0);
    }

    float lt = l_run + __shfl_xor(l_run, 16);
    lt += __shfl_xor(lt, 32);
    float rl[4];
#pragma unroll
    for (int r = 0; r < 4; ++r) rl[r] = 1.0f / __shfl(lt, lgrp * 4 + r);

    // compact hi-only epilogue
#pragma unroll
    for (int n = 0; n < 4; n++) {
#pragma unroll
        for (int r = 0; r < 4; r++) {
            float val = o_acc[n][r] * rl[r];
            int ia = qt * 128 + w * 16 + lgrp * 4 + r;
            size_t m = (size_t)b * 1024 + ia;
            int col = h * 64 + n * 16 + lrow;
            A3[m * 1024 + col] = f2bf(val);
        }
    }
}

extern "C" void kernel_launch(void* const* d_in, const int* in_sizes, int n_in,
                              void* d_out, int out_size, void* d_ws,
                              size_t ws_size, hipStream_t stream) {
    const float* x = (const float*)d_in[0];
    const float* w_qkv = (const float*)d_in[1];
    const float* w_out = (const float*)d_in[2];
    const float* rel_bias = (const float*)d_in[3];
    float* out = (float*)d_out;

    char* ws = (char*)d_ws;
    size_t off = 0;
    auto alloc = [&](size_t bytes) {
        char* p = ws + off;
        off += (bytes + 255) & ~(size_t)255;
        return p;
    };
    unsigned short* A1h = (unsigned short*)alloc((size_t)4096 * 1024 * 2);
    unsigned short* W1h = (unsigned short*)alloc((size_t)3072 * 1024 * 2);
    unsigned short* Qb = (unsigned short*)alloc((size_t)64 * 1024 * 64 * 2);
    unsigned short* Kb = (unsigned short*)alloc((size_t)64 * 1024 * 64 * 2);
    unsigned short* Vb = (unsigned short*)alloc((size_t)64 * 1024 * 64 * 2);
    unsigned short* A3h = (unsigned short*)alloc((size_t)4096 * 1024 * 2);
    unsigned short* W3h = (unsigned short*)alloc((size_t)1024 * 1024 * 2);
    // V^T aliases A1h (8 MB each): A1h dead after gemm256_hi; transpose_v after.
    unsigned short* Vtg = A1h;

    hipLaunchKernelGGL(prep_hi_rows, dim3(1024), dim3(256), 0, stream, x, A1h,
                       4096 * 256);
    hipLaunchKernelGGL(prep_hi_wqkv, dim3(768), dim3(256), 0, stream, w_qkv,
                       W1h);
    hipLaunchKernelGGL(prep_hi_rows, dim3(256), dim3(256), 0, stream, w_out,
                       W3h, 1024 * 256);
    hipLaunchKernelGGL(gemm256_hi, dim3(12, 16), dim3(512), 0, stream, A1h, W1h,
                       Qb, Kb, Vb);
    hipLaunchKernelGGL(transpose_v, dim3(16, 64), dim3(256), 0, stream, Vb, Vtg);
    hipLaunchKernelGGL(attn_kernel, dim3(8, 64), dim3(512), 0, stream, Qb, Kb,
                       Vtg, rel_bias, A3h);
    hipLaunchKernelGGL(gemm_out_v4, dim3(512), dim3(256), 0, stream, A3h, W3h,
                       out);
}

// Round 14
// 115.301 us; speedup vs baseline: 1.6862x; 1.6862x over previous
//
#include <hip/hip_runtime.h>
#include <hip/hip_bf16.h>

typedef short bf16x8 __attribute__((ext_vector_type(8)));
typedef float f32x4  __attribute__((ext_vector_type(4)));

typedef __attribute__((address_space(3))) void lds_t;
typedef __attribute__((address_space(1))) void gbl_t;

#define MFMA16(a,b,c) __builtin_amdgcn_mfma_f32_16x16x32_bf16((a),(b),(c),0,0,0)

__device__ __forceinline__ unsigned short f2bf(float f) {
    __hip_bfloat16 h = __float2bfloat16(f);
    return __builtin_bit_cast(unsigned short, h);
}
__device__ __forceinline__ float bf2f(unsigned short u) {
    __hip_bfloat16 h = __builtin_bit_cast(__hip_bfloat16, u);
    return __bfloat162float(h);
}

// f32 [R][1024] -> bf16 hi-only compact [R][1024].  float4 vectorized.
__global__ void prep_hi_rows(const float* __restrict__ src,
                             unsigned short* __restrict__ dst, int total4) {
    for (int idx = blockIdx.x * blockDim.x + threadIdx.x; idx < total4;
         idx += gridDim.x * blockDim.x) {
        int base = idx * 4;
        float4 v = *reinterpret_cast<const float4*>(src + base);
        ushort4 hi;
        hi.x = f2bf(v.x);
        hi.y = f2bf(v.y);
        hi.z = f2bf(v.z);
        hi.w = f2bf(v.w);
        *reinterpret_cast<ushort4*>(dst + base) = hi;
    }
}

// w_qkv [3072][1024], einops row permute (out row n = which*1024+h*64+d reads
// src row d*48+which*16+h) -> bf16 hi-only compact [3072][1024].
__global__ void prep_hi_wqkv(const float* __restrict__ w,
                             unsigned short* __restrict__ dst) {
    for (int idx = blockIdx.x * blockDim.x + threadIdx.x; idx < 3072 * 256;
         idx += gridDim.x * blockDim.x) {
        int base = idx * 4;
        int n = base >> 10, c = base & 1023;
        int d = n & 63, which = n >> 10, h = (n >> 6) & 15;
        int srow = d * 48 + which * 16 + h;
        float4 v = *reinterpret_cast<const float4*>(w + (size_t)srow * 1024 + c);
        ushort4 hi;
        hi.x = f2bf(v.x);
        hi.y = f2bf(v.y);
        hi.z = f2bf(v.z);
        hi.w = f2bf(v.w);
        *reinterpret_cast<ushort4*>(dst + (size_t)n * 1024 + c) = hi;
    }
}

// ============================================================================
// 256x256 hi-only bf16 GEMM for QKV (R10 structure + R14 depth-3 prefetch).
// R13 post-mortem: de-staged attn regressed (K/V don't fit L1; staging IS the
// prefetch pipeline).  R14 GEMM theory: step time 2470cy >> MFMA 300cy — the
// vmcnt wait is load latency (slot s+1 issued only 1 step earlier).  4-slot
// ring allows depth-3 at zero LDS cost: prologue stages slots 0,1,2; step s
// stages s+3; wait targets slot s+1 (issued at s-2, two steps of budget).
// Tail counts derived: s<=28 vmcnt(8), s==29 vmcnt(4), s==30 vmcnt(0).
// grid (12,16), 8 waves (2Mx4N), wave tile 128x64, acc[8][4], XOR swizzle.
// ============================================================================
__global__ __launch_bounds__(512, 2) void gemm256_hi(
    const unsigned short* __restrict__ A, const unsigned short* __restrict__ B,
    unsigned short* __restrict__ outQ, unsigned short* __restrict__ outK,
    unsigned short* __restrict__ outV) {
    __shared__ unsigned short lds[65536];  // A ring [0,32768), B ring [32768,65536)
    const int tid = threadIdx.x;
    const int wid = tid >> 6, lane = tid & 63;
    const int lrow = lane & 15, lgrp = lane >> 4;
    const int wr = wid >> 2, wc = wid & 3;
    const int mtile = blockIdx.y * 256, ntile = blockIdx.x * 256;

    const int csw = lgrp ^ ((lrow >> 1) & 3);
    const int aoff = (wr * 128 + lrow) * 32 + csw * 8;
    const int boff = 32768 + (wc * 64 + lrow) * 32 + csw * 8;

    const int sreg = wid * 2;
    const int srow0 = sreg * 16 + (lane >> 2);
    const int srow1 = (sreg + 1) * 16 + (lane >> 2);
    const int schunk = (lane & 3) ^ ((lane >> 3) & 3);
    const int sdst0 = sreg * 512;

    f32x4 acc[8][4];
#pragma unroll
    for (int i = 0; i < 8; ++i)
#pragma unroll
        for (int j = 0; j < 4; ++j) {
            f32x4 z = {0.f, 0.f, 0.f, 0.f};
            acc[i][j] = z;
        }

    // prologue: stage steps 0,1,2 into slots 0,1,2 (depth-3)
#pragma unroll
    for (int s0 = 0; s0 < 3; ++s0) {
        const int kb = s0 * 32;
        __builtin_amdgcn_global_load_lds(
            (const gbl_t*)(A + (size_t)(mtile + srow0) * 1024 + kb + schunk * 8),
            (lds_t*)(lds + s0 * 8192 + sdst0), 16, 0, 0);
        __builtin_amdgcn_global_load_lds(
            (const gbl_t*)(A + (size_t)(mtile + srow1) * 1024 + kb + schunk * 8),
            (lds_t*)(lds + s0 * 8192 + sdst0 + 512), 16, 0, 0);
        __builtin_amdgcn_global_load_lds(
            (const gbl_t*)(B + (size_t)(ntile + srow0) * 1024 + kb + schunk * 8),
            (lds_t*)(lds + 32768 + s0 * 8192 + sdst0), 16, 0, 0);
        __builtin_amdgcn_global_load_lds(
            (const gbl_t*)(B + (size_t)(ntile + srow1) * 1024 + kb + schunk * 8),
            (lds_t*)(lds + 32768 + s0 * 8192 + sdst0 + 512), 16, 0, 0);
    }
    asm volatile("s_waitcnt vmcnt(8)" ::: "memory");  // slot 0 landed
    __syncthreads();

    for (int s = 0; s < 32; ++s) {
        const int sa = s & 3;
        const unsigned short* sbase = lds + sa * 8192;

        bf16x8 af[8];
#pragma unroll
        for (int i = 0; i < 8; ++i)
            af[i] = *reinterpret_cast<const bf16x8*>(sbase + aoff + i * 512);
        bf16x8 b0 = *reinterpret_cast<const bf16x8*>(sbase + boff);
        bf16x8 b1 = *reinterpret_cast<const bf16x8*>(sbase + boff + 512);

        if (s <= 28) {
            const int kb2 = (s + 3) * 32;
            const int s2 = (s + 3) & 3;
            __builtin_amdgcn_global_load_lds(
                (const gbl_t*)(A + (size_t)(mtile + srow0) * 1024 + kb2 + schunk * 8),
                (lds_t*)(lds + s2 * 8192 + sdst0), 16, 0, 0);
            __builtin_amdgcn_global_load_lds(
                (const gbl_t*)(A + (size_t)(mtile + srow1) * 1024 + kb2 + schunk * 8),
                (lds_t*)(lds + s2 * 8192 + sdst0 + 512), 16, 0, 0);
        }
        __builtin_amdgcn_s_setprio(1);
#pragma unroll
        for (int i = 0; i < 8; ++i) {
            acc[i][0] = MFMA16(af[i], b0, acc[i][0]);
            acc[i][1] = MFMA16(af[i], b1, acc[i][1]);
        }
        __builtin_amdgcn_s_setprio(0);

        bf16x8 b2 = *reinterpret_cast<const bf16x8*>(sbase + boff + 1024);
        bf16x8 b3 = *reinterpret_cast<const bf16x8*>(sbase + boff + 1536);
        if (s <= 28) {
            const int kb2 = (s + 3) * 32;
            const int s2 = (s + 3) & 3;
            __builtin_amdgcn_global_load_lds(
                (const gbl_t*)(B + (size_t)(ntile + srow0) * 1024 + kb2 + schunk * 8),
                (lds_t*)(lds + 32768 + s2 * 8192 + sdst0), 16, 0, 0);
            __builtin_amdgcn_global_load_lds(
                (const gbl_t*)(B + (size_t)(ntile + srow1) * 1024 + kb2 + schunk * 8),
                (lds_t*)(lds + 32768 + s2 * 8192 + sdst0 + 512), 16, 0, 0);
        }
        __builtin_amdgcn_s_setprio(1);
#pragma unroll
        for (int i = 0; i < 8; ++i) {
            acc[i][2] = MFMA16(af[i], b2, acc[i][2]);
            acc[i][3] = MFMA16(af[i], b3, acc[i][3]);
        }
        __builtin_amdgcn_s_setprio(0);

        // wait: slot s+1 (issued at s-2) landed.  Newer in flight:
        // s<=28: stages at s-1 and s (8 loads); s==29: only s-1's (4); s==30: 0.
        if (s < 31) {
            if (s <= 28)
                asm volatile("s_waitcnt vmcnt(8)" ::: "memory");
            else if (s == 29)
                asm volatile("s_waitcnt vmcnt(4)" ::: "memory");
            else
                asm volatile("s_waitcnt vmcnt(0)" ::: "memory");
            __syncthreads();
        }
    }

#pragma unroll
    for (int i = 0; i < 8; ++i) {
#pragma unroll
        for (int j = 0; j < 4; ++j) {
#pragma unroll
            for (int r = 0; r < 4; ++r) {
                float v = acc[i][j][r];
                int m = mtile + wr * 128 + i * 16 + lgrp * 4 + r;
                int n = ntile + wc * 64 + j * 16 + lrow;
                int which = n >> 10;
                int hh = (n >> 6) & 15;
                int d = n & 63;
                int b = m >> 10, t = m & 1023;
                unsigned short* dstp =
                    (which == 0) ? outQ : ((which == 1) ? outK : outV);
                dstp[((size_t)((b << 4) + hh) * 1024 + t) * 64 + d] = f2bf(v);
            }
        }
    }
}

// ============================================================================
// Out-projection GEMM v4 + R14 depth-3 prefetch (same mechanism as gemm256).
// hi-only bf16, K=1024, 64x128 tile, 512 blocks, 4-slot ring, XCD swizzle.
// Tail counts (3 loads/step): s<=28 vmcnt(6), s==29 vmcnt(3), s==30 vmcnt(0).
// ============================================================================
__global__ __launch_bounds__(256, 3) void gemm_out_v4(
    const unsigned short* __restrict__ A, const unsigned short* __restrict__ B,
    float* __restrict__ outF) {
    __shared__ unsigned short As[4][64 * 32];   // 16 KB ring
    __shared__ unsigned short Bs[4][128 * 32];  // 32 KB ring
    const int tid = threadIdx.x;
    const int wid = tid >> 6, lane = tid & 63;
    const int lrow = lane & 15, lgrp = lane >> 4;
    const int wr = wid >> 1, wc = wid & 1;
    const int h = blockIdx.x;
    const int xcd = h & 7, within = h >> 3;
    const int mtile = (xcd * 8 + (within & 7)) * 64;
    const int ntile = (within >> 3) * 128;

    const int csw = lgrp ^ ((lrow >> 1) & 3);
    const int aoff = (wr * 32 + lrow) * 32 + csw * 8;  // + i*512
    const int boff = (wc * 64 + lrow) * 32 + csw * 8;  // + j*512

    const int srow = tid >> 2;                        // 0..63
    const int schunk = (tid & 3) ^ ((tid >> 3) & 3);  // inverse-swizzled src
    const unsigned short* Arow = A + (size_t)(mtile + srow) * 1024 + schunk * 8;
    const unsigned short* Brow0 = B + (size_t)(ntile + srow) * 1024 + schunk * 8;
    const unsigned short* Brow1 =
        B + (size_t)(ntile + 64 + srow) * 1024 + schunk * 8;

    f32x4 acc[2][4];
#pragma unroll
    for (int i = 0; i < 2; ++i)
#pragma unroll
        for (int j = 0; j < 4; ++j) {
            f32x4 z = {0.f, 0.f, 0.f, 0.f};
            acc[i][j] = z;
        }

    // prologue: stage steps 0,1,2 (depth-3)
#pragma unroll
    for (int s0 = 0; s0 < 3; ++s0) {
        const int kb = s0 * 32;
        __builtin_amdgcn_global_load_lds((const gbl_t*)(Arow + kb),
                                         (lds_t*)(&As[s0][0] + tid * 8), 16, 0,
                                         0);
        __builtin_amdgcn_global_load_lds((const gbl_t*)(Brow0 + kb),
                                         (lds_t*)(&Bs[s0][0] + tid * 8), 16, 0,
                                         0);
        __builtin_amdgcn_global_load_lds((const gbl_t*)(Brow1 + kb),
                                         (lds_t*)(&Bs[s0][0] + 2048 + tid * 8),
                                         16, 0, 0);
    }
    asm volatile("s_waitcnt vmcnt(6)" ::: "memory");  // slot 0 landed
    __syncthreads();

    for (int s = 0; s < 32; ++s) {
        const int sa = s & 3;
        if (s <= 28) {
            const int kb = (s + 3) * 32;
            const int s2 = (s + 3) & 3;
            __builtin_amdgcn_global_load_lds((const gbl_t*)(Arow + kb),
                                             (lds_t*)(&As[s2][0] + tid * 8), 16,
                                             0, 0);
            __builtin_amdgcn_global_load_lds((const gbl_t*)(Brow0 + kb),
                                             (lds_t*)(&Bs[s2][0] + tid * 8), 16,
                                             0, 0);
            __builtin_amdgcn_global_load_lds(
                (const gbl_t*)(Brow1 + kb),
                (lds_t*)(&Bs[s2][0] + 2048 + tid * 8), 16, 0, 0);
        }
        bf16x8 af[2], bfv[4];
#pragma unroll
        for (int i = 0; i < 2; ++i)
            af[i] = *reinterpret_cast<const bf16x8*>(&As[sa][0] + aoff + i * 512);
#pragma unroll
        for (int j = 0; j < 4; ++j)
            bfv[j] =
                *reinterpret_cast<const bf16x8*>(&Bs[sa][0] + boff + j * 512);
        __builtin_amdgcn_s_setprio(1);
#pragma unroll
        for (int i = 0; i < 2; ++i)
#pragma unroll
            for (int j = 0; j < 4; ++j)
                acc[i][j] = MFMA16(af[i], bfv[j], acc[i][j]);
        __builtin_amdgcn_s_setprio(0);
        if (s < 31) {
            if (s <= 28)
                asm volatile("s_waitcnt vmcnt(6)" ::: "memory");
            else if (s == 29)
                asm volatile("s_waitcnt vmcnt(3)" ::: "memory");
            else
                asm volatile("s_waitcnt vmcnt(0)" ::: "memory");
            __syncthreads();
        }
    }

#pragma unroll
    for (int i = 0; i < 2; ++i)
#pragma unroll
        for (int j = 0; j < 4; ++j)
#pragma unroll
            for (int r = 0; r < 4; ++r) {
                int m = mtile + wr * 32 + i * 16 + lgrp * 4 + r;
                int n = ntile + wc * 64 + j * 16 + lrow;
                outF[(size_t)m * 1024 + n] = acc[i][j][r];
            }
}

// V [bh][1024][64] -> V^T [bh][64][1024], LDS-tiled, coalesced both sides.
__global__ __launch_bounds__(256) void transpose_v(
    const unsigned short* __restrict__ Vb, unsigned short* __restrict__ Vtg) {
    __shared__ unsigned short L[64][72];
    const int tt = blockIdx.x, bh = blockIdx.y;
    const int tid = threadIdx.x;
#pragma unroll
    for (int e = 0; e < 2; ++e) {
        int chunk = e * 256 + tid;
        int r = chunk >> 3, c = (chunk & 7) * 8;
        uint4 v = *reinterpret_cast<const uint4*>(
            Vb + ((size_t)bh * 1024 + tt * 64 + r) * 64 + c);
        *reinterpret_cast<uint4*>(&L[r][c]) = v;
    }
    __syncthreads();
#pragma unroll
    for (int e = 0; e < 2; ++e) {
        int chunk = e * 256 + tid;
        int d = chunk >> 3, t0 = (chunk & 7) * 8;
        unsigned short tmp[8];
#pragma unroll
        for (int u = 0; u < 8; ++u) tmp[u] = L[t0 + u][d];
        *reinterpret_cast<uint4*>(Vtg + ((size_t)bh * 64 + d) * 1024 + tt * 64 +
                                  t0) = *reinterpret_cast<const uint4*>(tmp);
    }
}

// ============================================================================
// Flash attention (exact R10 structure — R13's de-staged variant regressed
// 38->124us: K/V don't fit L1, and LDS staging is the prefetch pipeline).
// QBLK=128, 8 waves, swapped QK^T, exp2 softmax, defer-max, cvt_pk P-pack,
// K/V dbuf via global_load_lds, XOR swizzle.
// ============================================================================
__global__ __launch_bounds__(512) void attn_kernel(
    const unsigned short* __restrict__ Qb, const unsigned short* __restrict__ Kb,
    const unsigned short* __restrict__ Vtg, const float* __restrict__ rel_bias,
    unsigned short* __restrict__ A3) {
    const int qt = blockIdx.x;  // 0..7 (128 q-rows each)
    const int bh = blockIdx.y;  // 0..63
    const int b = bh >> 4, h = bh & 15;
    const int tid = threadIdx.x;
    const int w = tid >> 6, lane = tid & 63;  // w in 0..7
    const int lrow = lane & 15, lgrp = lane >> 4;
    const float LOG2E = 1.4426950408889634f;
    const float SCALE2 = 0.125f * 1.4426950408889634f;
    const float THR = 11.5f;  // ~8 nats in exp2 units

    __shared__ unsigned short Ks[2][64 * 64];  // 16 KB
    __shared__ unsigned short Vs[2][64 * 64];  // 16 KB
    __shared__ unsigned short Ps[8][16 * 64];  // 16 KB
    __shared__ float Bias2[2][192];

    const unsigned short* Ktile = Kb + (size_t)bh * 1024 * 64;
    const unsigned short* Vtile = Vtg + (size_t)bh * 64 * 1024;

    const unsigned short* Qp =
        Qb + ((size_t)bh * 1024 + qt * 128 + w * 16 + lrow) * 64;
    bf16x8 qa0 = *reinterpret_cast<const bf16x8*>(Qp + lgrp * 8);
    bf16x8 qa1 = *reinterpret_cast<const bf16x8*>(Qp + 32 + lgrp * 8);

    const int sr0 = w * 8 + (lane >> 3);
    const int sc_lo = lane & 7;

    float m_run = -3.0e38f;
    float l_run = 0.f;
    f32x4 o_acc[4];
#pragma unroll
    for (int n = 0; n < 4; n++) {
        f32x4 z = {0.f, 0.f, 0.f, 0.f};
        o_acc[n] = z;
    }

    const int bbase = lgrp * 4 + 127 - w * 16 - lrow;

    {
        {
            int r = sr0;
            int c = sc_lo ^ (r & 7);
            __builtin_amdgcn_global_load_lds(
                (const gbl_t*)(Ktile + (size_t)r * 64 + c * 8),
                (lds_t*)(&Ks[0][0] + w * 512), 16, 0, 0);
            __builtin_amdgcn_global_load_lds(
                (const gbl_t*)(Vtile + (size_t)r * 1024 + c * 8),
                (lds_t*)(&Vs[0][0] + w * 512), 16, 0, 0);
        }
        if (tid < 192) {
            int rowi = 0 - qt * 128 + 896 + tid;
            rowi = (rowi < 2046) ? rowi : 2046;
            Bias2[0][tid] = rel_bias[(size_t)rowi * 16 + h] * LOG2E;
        }
        asm volatile("s_waitcnt vmcnt(0)" ::: "memory");
        __syncthreads();
    }

    for (int kv = 0; kv < 16; ++kv) {
        const int cur = kv & 1;
        if (kv < 15) {
            const int j0n = (kv + 1) * 64;
            int r = sr0;
            int c = sc_lo ^ (r & 7);
            __builtin_amdgcn_global_load_lds(
                (const gbl_t*)(Ktile + (size_t)(j0n + r) * 64 + c * 8),
                (lds_t*)(&Ks[cur ^ 1][0] + w * 512), 16, 0, 0);
            __builtin_amdgcn_global_load_lds(
                (const gbl_t*)(Vtile + (size_t)r * 1024 + j0n + c * 8),
                (lds_t*)(&Vs[cur ^ 1][0] + w * 512), 16, 0, 0);
            if (tid < 192) {
                int rowi = j0n - qt * 128 + 896 + tid;
                rowi = (rowi < 2046) ? rowi : 2046;
                Bias2[cur ^ 1][tid] = rel_bias[(size_t)rowi * 16 + h] * LOG2E;
            }
        }

        const unsigned short* kbuf = &Ks[cur][0];
        f32x4 s[4];
        __builtin_amdgcn_s_setprio(1);
#pragma unroll
        for (int f = 0; f < 4; ++f) {
            int krow = f * 16 + lrow;
            int sw0 = (lgrp ^ (lrow & 7)) * 8;
            int sw1 = ((4 | lgrp) ^ (lrow & 7)) * 8;
            bf16x8 kb0 = *reinterpret_cast<const bf16x8*>(kbuf + krow * 64 + sw0);
            bf16x8 kb1 = *reinterpret_cast<const bf16x8*>(kbuf + krow * 64 + sw1);
            f32x4 z = {0.f, 0.f, 0.f, 0.f};
            z = MFMA16(kb0, qa0, z);
            z = MFMA16(kb1, qa1, z);
            s[f] = z;
        }
        __builtin_amdgcn_s_setprio(0);

        float x[4][4];
        float pm = -3.0e38f;
#pragma unroll
        for (int f = 0; f < 4; ++f)
#pragma unroll
            for (int r = 0; r < 4; ++r) {
                float xv = s[f][r] * SCALE2 + Bias2[cur][bbase + f * 16 + r];
                x[f][r] = xv;
                pm = fmaxf(pm, xv);
            }
        pm = fmaxf(pm, __shfl_xor(pm, 16));
        pm = fmaxf(pm, __shfl_xor(pm, 32));

        if (!__all(pm - m_run <= THR)) {
            float mnew = fmaxf(m_run, pm);
            float corr = __builtin_amdgcn_exp2f(m_run - mnew);
            m_run = mnew;
            l_run *= corr;
            float cb[4];
#pragma unroll
            for (int r = 0; r < 4; ++r) cb[r] = __shfl(corr, lgrp * 4 + r);
#pragma unroll
            for (int n = 0; n < 4; n++)
#pragma unroll
                for (int r = 0; r < 4; r++) o_acc[n][r] *= cb[r];
        }

        float su = 0.f;
#pragma unroll
        for (int f = 0; f < 4; ++f)
#pragma unroll
            for (int r = 0; r < 4; ++r) {
                float pv = __builtin_amdgcn_exp2f(x[f][r] - m_run);
                x[f][r] = pv;
                su += pv;
            }
        l_run += su;

#pragma unroll
        for (int f = 0; f < 4; ++f) {
            unsigned int plo, phi;
            asm("v_cvt_pk_bf16_f32 %0, %1, %2"
                : "=v"(plo)
                : "v"(x[f][0]), "v"(x[f][1]));
            asm("v_cvt_pk_bf16_f32 %0, %1, %2"
                : "=v"(phi)
                : "v"(x[f][2]), "v"(x[f][3]));
            const int chunk = (f * 2 + (lgrp >> 1)) ^ (lrow & 7);
            uint2 pw;
            pw.x = plo;
            pw.y = phi;
            *reinterpret_cast<uint2*>(
                &Ps[w][lrow * 64 + chunk * 8 + (lgrp & 1) * 4]) = pw;
        }

        const unsigned short* vbuf = &Vs[cur][0];
        __builtin_amdgcn_s_setprio(1);
#pragma unroll
        for (int jc = 0; jc < 2; ++jc) {
            int pc = ((4 * jc + lgrp) ^ (lrow & 7)) * 8;
            bf16x8 pa =
                *reinterpret_cast<const bf16x8*>(&Ps[w][0] + lrow * 64 + pc);
#pragma unroll
            for (int n = 0; n < 4; n++) {
                int vrow = n * 16 + lrow;
                bf16x8 vb =
                    *reinterpret_cast<const bf16x8*>(vbuf + vrow * 64 + pc);
                o_acc[n] = MFMA16(pa, vb, o_acc[n]);
            }
        }
        __builtin_amdgcn_s_setprio(0);

        if (kv < 15) {
            asm volatile("s_waitcnt vmcnt(0)" ::: "memory");
            __syncthreads();
        }
    }

    float lt = l_run + __shfl_xor(l_run, 16);
    lt += __shfl_xor(lt, 32);
    float rl[4];
#pragma unroll
    for (int r = 0; r < 4; ++r) rl[r] = 1.0f / __shfl(lt, lgrp * 4 + r);

    // compact hi-only epilogue
#pragma unroll
    for (int n = 0; n < 4; n++) {
#pragma unroll
        for (int r = 0; r < 4; r++) {
            float val = o_acc[n][r] * rl[r];
            int ia = qt * 128 + w * 16 + lgrp * 4 + r;
            size_t m = (size_t)b * 1024 + ia;
            int col = h * 64 + n * 16 + lrow;
            A3[m * 1024 + col] = f2bf(val);
        }
    }
}

extern "C" void kernel_launch(void* const* d_in, const int* in_sizes, int n_in,
                              void* d_out, int out_size, void* d_ws,
                              size_t ws_size, hipStream_t stream) {
    const float* x = (const float*)d_in[0];
    const float* w_qkv = (const float*)d_in[1];
    const float* w_out = (const float*)d_in[2];
    const float* rel_bias = (const float*)d_in[3];
    float* out = (float*)d_out;

    char* ws = (char*)d_ws;
    size_t off = 0;
    auto alloc = [&](size_t bytes) {
        char* p = ws + off;
        off += (bytes + 255) & ~(size_t)255;
        return p;
    };
    unsigned short* A1h = (unsigned short*)alloc((size_t)4096 * 1024 * 2);
    unsigned short* W1h = (unsigned short*)alloc((size_t)3072 * 1024 * 2);
    unsigned short* Qb = (unsigned short*)alloc((size_t)64 * 1024 * 64 * 2);
    unsigned short* Kb = (unsigned short*)alloc((size_t)64 * 1024 * 64 * 2);
    unsigned short* Vb = (unsigned short*)alloc((size_t)64 * 1024 * 64 * 2);
    unsigned short* A3h = (unsigned short*)alloc((size_t)4096 * 1024 * 2);
    unsigned short* W3h = (unsigned short*)alloc((size_t)1024 * 1024 * 2);
    // V^T aliases A1h (8 MB each): A1h dead after gemm256_hi; transpose_v after.
    unsigned short* Vtg = A1h;

    hipLaunchKernelGGL(prep_hi_rows, dim3(1024), dim3(256), 0, stream, x, A1h,
                       4096 * 256);
    hipLaunchKernelGGL(prep_hi_wqkv, dim3(768), dim3(256), 0, stream, w_qkv,
                       W1h);
    hipLaunchKernelGGL(prep_hi_rows, dim3(256), dim3(256), 0, stream, w_out,
                       W3h, 1024 * 256);
    hipLaunchKernelGGL(gemm256_hi, dim3(12, 16), dim3(512), 0, stream, A1h, W1h,
                       Qb, Kb, Vb);
    hipLaunchKernelGGL(transpose_v, dim3(16, 64), dim3(256), 0, stream, Vb, Vtg);
    hipLaunchKernelGGL(attn_kernel, dim3(8, 64), dim3(512), 0, stream, Qb, Kb,
                       Vtg, rel_bias, A3h);
    hipLaunchKernelGGL(gemm_out_v4, dim3(512), dim3(256), 0, stream, A3h, W3h,
                       out);
}

// Round 15
// 108.582 us; speedup vs baseline: 1.7906x; 1.0619x over previous
//
#include <hip/hip_runtime.h>
#include <hip/hip_bf16.h>

typedef short bf16x8 __attribute__((ext_vector_type(8)));
typedef float f32x4  __attribute__((ext_vector_type(4)));

typedef __attribute__((address_space(3))) void lds_t;
typedef __attribute__((address_space(1))) void gbl_t;

#define MFMA16(a,b,c) __builtin_amdgcn_mfma_f32_16x16x32_bf16((a),(b),(c),0,0,0)

__device__ __forceinline__ unsigned short f2bf(float f) {
    __hip_bfloat16 h = __float2bfloat16(f);
    return __builtin_bit_cast(unsigned short, h);
}
__device__ __forceinline__ float bf2f(unsigned short u) {
    __hip_bfloat16 h = __builtin_bit_cast(__hip_bfloat16, u);
    return __bfloat162float(h);
}

// ============================================================================
// R15: single fused prep kernel (was 3 kernels + 3 launch gaps).
// Segment 1: x [4096][1024] f32 -> A1h bf16 compact (identity layout).
// Segment 2: w_qkv with einops row permute -> W1h [3072][1024].
// Segment 3: w_out [1024][1024] -> W3h bf16 compact.
// All float4-vectorized; grid-stride; blocks mostly stay in one segment.
// ============================================================================
__global__ void prep_all(const float* __restrict__ x,
                         const float* __restrict__ w_qkv,
                         const float* __restrict__ w_out,
                         unsigned short* __restrict__ A1h,
                         unsigned short* __restrict__ W1h,
                         unsigned short* __restrict__ W3h) {
    const int NX = 4096 * 256, NW1 = 3072 * 256, NW3 = 1024 * 256;
    for (int idx = blockIdx.x * blockDim.x + threadIdx.x; idx < NX + NW1 + NW3;
         idx += gridDim.x * blockDim.x) {
        if (idx < NX) {
            int base = idx * 4;
            float4 v = *reinterpret_cast<const float4*>(x + base);
            ushort4 hi;
            hi.x = f2bf(v.x); hi.y = f2bf(v.y);
            hi.z = f2bf(v.z); hi.w = f2bf(v.w);
            *reinterpret_cast<ushort4*>(A1h + base) = hi;
        } else if (idx < NX + NW1) {
            int base = (idx - NX) * 4;
            int n = base >> 10, c = base & 1023;
            int d = n & 63, which = n >> 10, h = (n >> 6) & 15;
            int srow = d * 48 + which * 16 + h;
            float4 v =
                *reinterpret_cast<const float4*>(w_qkv + (size_t)srow * 1024 + c);
            ushort4 hi;
            hi.x = f2bf(v.x); hi.y = f2bf(v.y);
            hi.z = f2bf(v.z); hi.w = f2bf(v.w);
            *reinterpret_cast<ushort4*>(W1h + (size_t)n * 1024 + c) = hi;
        } else {
            int base = (idx - NX - NW1) * 4;
            float4 v = *reinterpret_cast<const float4*>(w_out + base);
            ushort4 hi;
            hi.x = f2bf(v.x); hi.y = f2bf(v.y);
            hi.z = f2bf(v.z); hi.w = f2bf(v.w);
            *reinterpret_cast<ushort4*>(W3h + base) = hi;
        }
    }
}

// ============================================================================
// 256x256 hi-only bf16 GEMM for QKV — exact R10 structure (measured best:
// 33us; R11 re-tile, R12 fused-V^T, R14 depth-3 all regressed or null).
// grid (12,16)=192 blocks, 512 thr / 8 waves (2Mx4N), wave tile 128x64,
// acc[8][4], 4-slot ring, depth-2, counted vmcnt(4), XOR swizzle.
// ============================================================================
__global__ __launch_bounds__(512, 2) void gemm256_hi(
    const unsigned short* __restrict__ A, const unsigned short* __restrict__ B,
    unsigned short* __restrict__ outQ, unsigned short* __restrict__ outK,
    unsigned short* __restrict__ outV) {
    __shared__ unsigned short lds[65536];  // A ring [0,32768), B ring [32768,65536)
    const int tid = threadIdx.x;
    const int wid = tid >> 6, lane = tid & 63;
    const int lrow = lane & 15, lgrp = lane >> 4;
    const int wr = wid >> 2, wc = wid & 3;
    const int mtile = blockIdx.y * 256, ntile = blockIdx.x * 256;

    const int csw = lgrp ^ ((lrow >> 1) & 3);
    const int aoff = (wr * 128 + lrow) * 32 + csw * 8;
    const int boff = 32768 + (wc * 64 + lrow) * 32 + csw * 8;

    const int sreg = wid * 2;
    const int srow0 = sreg * 16 + (lane >> 2);
    const int srow1 = (sreg + 1) * 16 + (lane >> 2);
    const int schunk = (lane & 3) ^ ((lane >> 3) & 3);
    const int sdst0 = sreg * 512;

    f32x4 acc[8][4];
#pragma unroll
    for (int i = 0; i < 8; ++i)
#pragma unroll
        for (int j = 0; j < 4; ++j) {
            f32x4 z = {0.f, 0.f, 0.f, 0.f};
            acc[i][j] = z;
        }

#pragma unroll
    for (int s0 = 0; s0 < 2; ++s0) {
        const int kb = s0 * 32;
        __builtin_amdgcn_global_load_lds(
            (const gbl_t*)(A + (size_t)(mtile + srow0) * 1024 + kb + schunk * 8),
            (lds_t*)(lds + s0 * 8192 + sdst0), 16, 0, 0);
        __builtin_amdgcn_global_load_lds(
            (const gbl_t*)(A + (size_t)(mtile + srow1) * 1024 + kb + schunk * 8),
            (lds_t*)(lds + s0 * 8192 + sdst0 + 512), 16, 0, 0);
        __builtin_amdgcn_global_load_lds(
            (const gbl_t*)(B + (size_t)(ntile + srow0) * 1024 + kb + schunk * 8),
            (lds_t*)(lds + 32768 + s0 * 8192 + sdst0), 16, 0, 0);
        __builtin_amdgcn_global_load_lds(
            (const gbl_t*)(B + (size_t)(ntile + srow1) * 1024 + kb + schunk * 8),
            (lds_t*)(lds + 32768 + s0 * 8192 + sdst0 + 512), 16, 0, 0);
    }
    asm volatile("s_waitcnt vmcnt(4)" ::: "memory");
    __syncthreads();

    for (int s = 0; s < 32; ++s) {
        const int sa = s & 3;
        const unsigned short* sbase = lds + sa * 8192;

        bf16x8 af[8];
#pragma unroll
        for (int i = 0; i < 8; ++i)
            af[i] = *reinterpret_cast<const bf16x8*>(sbase + aoff + i * 512);
        bf16x8 b0 = *reinterpret_cast<const bf16x8*>(sbase + boff);
        bf16x8 b1 = *reinterpret_cast<const bf16x8*>(sbase + boff + 512);

        if (s <= 29) {
            const int kb2 = (s + 2) * 32;
            const int s2 = (s + 2) & 3;
            __builtin_amdgcn_global_load_lds(
                (const gbl_t*)(A + (size_t)(mtile + srow0) * 1024 + kb2 + schunk * 8),
                (lds_t*)(lds + s2 * 8192 + sdst0), 16, 0, 0);
            __builtin_amdgcn_global_load_lds(
                (const gbl_t*)(A + (size_t)(mtile + srow1) * 1024 + kb2 + schunk * 8),
                (lds_t*)(lds + s2 * 8192 + sdst0 + 512), 16, 0, 0);
        }
        __builtin_amdgcn_s_setprio(1);
#pragma unroll
        for (int i = 0; i < 8; ++i) {
            acc[i][0] = MFMA16(af[i], b0, acc[i][0]);
            acc[i][1] = MFMA16(af[i], b1, acc[i][1]);
        }
        __builtin_amdgcn_s_setprio(0);

        bf16x8 b2 = *reinterpret_cast<const bf16x8*>(sbase + boff + 1024);
        bf16x8 b3 = *reinterpret_cast<const bf16x8*>(sbase + boff + 1536);
        if (s <= 29) {
            const int kb2 = (s + 2) * 32;
            const int s2 = (s + 2) & 3;
            __builtin_amdgcn_global_load_lds(
                (const gbl_t*)(B + (size_t)(ntile + srow0) * 1024 + kb2 + schunk * 8),
                (lds_t*)(lds + 32768 + s2 * 8192 + sdst0), 16, 0, 0);
            __builtin_amdgcn_global_load_lds(
                (const gbl_t*)(B + (size_t)(ntile + srow1) * 1024 + kb2 + schunk * 8),
                (lds_t*)(lds + 32768 + s2 * 8192 + sdst0 + 512), 16, 0, 0);
        }
        __builtin_amdgcn_s_setprio(1);
#pragma unroll
        for (int i = 0; i < 8; ++i) {
            acc[i][2] = MFMA16(af[i], b2, acc[i][2]);
            acc[i][3] = MFMA16(af[i], b3, acc[i][3]);
        }
        __builtin_amdgcn_s_setprio(0);

        if (s < 31) {
            if (s <= 29)
                asm volatile("s_waitcnt vmcnt(4)" ::: "memory");
            else
                asm volatile("s_waitcnt vmcnt(0)" ::: "memory");
            __syncthreads();
        }
    }

#pragma unroll
    for (int i = 0; i < 8; ++i) {
#pragma unroll
        for (int j = 0; j < 4; ++j) {
#pragma unroll
            for (int r = 0; r < 4; ++r) {
                float v = acc[i][j][r];
                int m = mtile + wr * 128 + i * 16 + lgrp * 4 + r;
                int n = ntile + wc * 64 + j * 16 + lrow;
                int which = n >> 10;
                int hh = (n >> 6) & 15;
                int d = n & 63;
                int b = m >> 10, t = m & 1023;
                unsigned short* dstp =
                    (which == 0) ? outQ : ((which == 1) ? outK : outV);
                dstp[((size_t)((b << 4) + hh) * 1024 + t) * 64 + d] = f2bf(v);
            }
        }
    }
}

// ============================================================================
// Out-projection GEMM v4 — exact R9/R10 structure (measured best ~20us;
// R14 depth-3 was null).  hi-only bf16, K=1024, 64x128 tile, 512 blocks,
// 4-slot ring, depth-2, counted vmcnt(3), XCD swizzle, 0 conflicts.
// ============================================================================
__global__ __launch_bounds__(256, 3) void gemm_out_v4(
    const unsigned short* __restrict__ A, const unsigned short* __restrict__ B,
    float* __restrict__ outF) {
    __shared__ unsigned short As[4][64 * 32];   // 16 KB ring
    __shared__ unsigned short Bs[4][128 * 32];  // 32 KB ring
    const int tid = threadIdx.x;
    const int wid = tid >> 6, lane = tid & 63;
    const int lrow = lane & 15, lgrp = lane >> 4;
    const int wr = wid >> 1, wc = wid & 1;
    const int h = blockIdx.x;
    const int xcd = h & 7, within = h >> 3;
    const int mtile = (xcd * 8 + (within & 7)) * 64;
    const int ntile = (within >> 3) * 128;

    const int csw = lgrp ^ ((lrow >> 1) & 3);
    const int aoff = (wr * 32 + lrow) * 32 + csw * 8;  // + i*512
    const int boff = (wc * 64 + lrow) * 32 + csw * 8;  // + j*512

    const int srow = tid >> 2;                        // 0..63
    const int schunk = (tid & 3) ^ ((tid >> 3) & 3);  // inverse-swizzled src
    const unsigned short* Arow = A + (size_t)(mtile + srow) * 1024 + schunk * 8;
    const unsigned short* Brow0 = B + (size_t)(ntile + srow) * 1024 + schunk * 8;
    const unsigned short* Brow1 =
        B + (size_t)(ntile + 64 + srow) * 1024 + schunk * 8;

    f32x4 acc[2][4];
#pragma unroll
    for (int i = 0; i < 2; ++i)
#pragma unroll
        for (int j = 0; j < 4; ++j) {
            f32x4 z = {0.f, 0.f, 0.f, 0.f};
            acc[i][j] = z;
        }

#pragma unroll
    for (int s0 = 0; s0 < 2; ++s0) {
        const int kb = s0 * 32;
        __builtin_amdgcn_global_load_lds((const gbl_t*)(Arow + kb),
                                         (lds_t*)(&As[s0][0] + tid * 8), 16, 0,
                                         0);
        __builtin_amdgcn_global_load_lds((const gbl_t*)(Brow0 + kb),
                                         (lds_t*)(&Bs[s0][0] + tid * 8), 16, 0,
                                         0);
        __builtin_amdgcn_global_load_lds((const gbl_t*)(Brow1 + kb),
                                         (lds_t*)(&Bs[s0][0] + 2048 + tid * 8),
                                         16, 0, 0);
    }
    asm volatile("s_waitcnt vmcnt(3)" ::: "memory");  // slot 0 landed
    __syncthreads();

    for (int s = 0; s < 32; ++s) {
        const int sa = s & 3;
        if (s <= 29) {
            const int kb = (s + 2) * 32;
            const int s2 = (s + 2) & 3;
            __builtin_amdgcn_global_load_lds((const gbl_t*)(Arow + kb),
                                             (lds_t*)(&As[s2][0] + tid * 8), 16,
                                             0, 0);
            __builtin_amdgcn_global_load_lds((const gbl_t*)(Brow0 + kb),
                                             (lds_t*)(&Bs[s2][0] + tid * 8), 16,
                                             0, 0);
            __builtin_amdgcn_global_load_lds(
                (const gbl_t*)(Brow1 + kb),
                (lds_t*)(&Bs[s2][0] + 2048 + tid * 8), 16, 0, 0);
        }
        bf16x8 af[2], bfv[4];
#pragma unroll
        for (int i = 0; i < 2; ++i)
            af[i] = *reinterpret_cast<const bf16x8*>(&As[sa][0] + aoff + i * 512);
#pragma unroll
        for (int j = 0; j < 4; ++j)
            bfv[j] =
                *reinterpret_cast<const bf16x8*>(&Bs[sa][0] + boff + j * 512);
        __builtin_amdgcn_s_setprio(1);
#pragma unroll
        for (int i = 0; i < 2; ++i)
#pragma unroll
            for (int j = 0; j < 4; ++j)
                acc[i][j] = MFMA16(af[i], bfv[j], acc[i][j]);
        __builtin_amdgcn_s_setprio(0);
        if (s < 31) {
            if (s <= 29)
                asm volatile("s_waitcnt vmcnt(3)" ::: "memory");
            else
                asm volatile("s_waitcnt vmcnt(0)" ::: "memory");
            __syncthreads();
        }
    }

#pragma unroll
    for (int i = 0; i < 2; ++i)
#pragma unroll
        for (int j = 0; j < 4; ++j)
#pragma unroll
            for (int r = 0; r < 4; ++r) {
                int m = mtile + wr * 32 + i * 16 + lgrp * 4 + r;
                int n = ntile + wc * 64 + j * 16 + lrow;
                outF[(size_t)m * 1024 + n] = acc[i][j][r];
            }
}

// V [bh][1024][64] -> V^T [bh][64][1024], LDS-tiled, coalesced both sides.
__global__ __launch_bounds__(256) void transpose_v(
    const unsigned short* __restrict__ Vb, unsigned short* __restrict__ Vtg) {
    __shared__ unsigned short L[64][72];
    const int tt = blockIdx.x, bh = blockIdx.y;
    const int tid = threadIdx.x;
#pragma unroll
    for (int e = 0; e < 2; ++e) {
        int chunk = e * 256 + tid;
        int r = chunk >> 3, c = (chunk & 7) * 8;
        uint4 v = *reinterpret_cast<const uint4*>(
            Vb + ((size_t)bh * 1024 + tt * 64 + r) * 64 + c);
        *reinterpret_cast<uint4*>(&L[r][c]) = v;
    }
    __syncthreads();
#pragma unroll
    for (int e = 0; e < 2; ++e) {
        int chunk = e * 256 + tid;
        int d = chunk >> 3, t0 = (chunk & 7) * 8;
        unsigned short tmp[8];
#pragma unroll
        for (int u = 0; u < 8; ++u) tmp[u] = L[t0 + u][d];
        *reinterpret_cast<uint4*>(Vtg + ((size_t)bh * 64 + d) * 1024 + tt * 64 +
                                  t0) = *reinterpret_cast<const uint4*>(tmp);
    }
}

// ============================================================================
// Flash attention — exact R10 structure (measured best ~38us; R13 de-staging
// regressed 3x: K/V don't fit L1 and LDS staging IS the prefetch pipeline).
// QBLK=128, 8 waves, swapped QK^T, exp2 softmax, defer-max, cvt_pk P-pack,
// K/V dbuf via global_load_lds, XOR swizzle.
// ============================================================================
__global__ __launch_bounds__(512) void attn_kernel(
    const unsigned short* __restrict__ Qb, const unsigned short* __restrict__ Kb,
    const unsigned short* __restrict__ Vtg, const float* __restrict__ rel_bias,
    unsigned short* __restrict__ A3) {
    const int qt = blockIdx.x;  // 0..7 (128 q-rows each)
    const int bh = blockIdx.y;  // 0..63
    const int b = bh >> 4, h = bh & 15;
    const int tid = threadIdx.x;
    const int w = tid >> 6, lane = tid & 63;  // w in 0..7
    const int lrow = lane & 15, lgrp = lane >> 4;
    const float LOG2E = 1.4426950408889634f;
    const float SCALE2 = 0.125f * 1.4426950408889634f;
    const float THR = 11.5f;  // ~8 nats in exp2 units

    __shared__ unsigned short Ks[2][64 * 64];  // 16 KB
    __shared__ unsigned short Vs[2][64 * 64];  // 16 KB
    __shared__ unsigned short Ps[8][16 * 64];  // 16 KB
    __shared__ float Bias2[2][192];

    const unsigned short* Ktile = Kb + (size_t)bh * 1024 * 64;
    const unsigned short* Vtile = Vtg + (size_t)bh * 64 * 1024;

    const unsigned short* Qp =
        Qb + ((size_t)bh * 1024 + qt * 128 + w * 16 + lrow) * 64;
    bf16x8 qa0 = *reinterpret_cast<const bf16x8*>(Qp + lgrp * 8);
    bf16x8 qa1 = *reinterpret_cast<const bf16x8*>(Qp + 32 + lgrp * 8);

    const int sr0 = w * 8 + (lane >> 3);
    const int sc_lo = lane & 7;

    float m_run = -3.0e38f;
    float l_run = 0.f;
    f32x4 o_acc[4];
#pragma unroll
    for (int n = 0; n < 4; n++) {
        f32x4 z = {0.f, 0.f, 0.f, 0.f};
        o_acc[n] = z;
    }

    const int bbase = lgrp * 4 + 127 - w * 16 - lrow;

    {
        {
            int r = sr0;
            int c = sc_lo ^ (r & 7);
            __builtin_amdgcn_global_load_lds(
                (const gbl_t*)(Ktile + (size_t)r * 64 + c * 8),
                (lds_t*)(&Ks[0][0] + w * 512), 16, 0, 0);
            __builtin_amdgcn_global_load_lds(
                (const gbl_t*)(Vtile + (size_t)r * 1024 + c * 8),
                (lds_t*)(&Vs[0][0] + w * 512), 16, 0, 0);
        }
        if (tid < 192) {
            int rowi = 0 - qt * 128 + 896 + tid;
            rowi = (rowi < 2046) ? rowi : 2046;
            Bias2[0][tid] = rel_bias[(size_t)rowi * 16 + h] * LOG2E;
        }
        asm volatile("s_waitcnt vmcnt(0)" ::: "memory");
        __syncthreads();
    }

    for (int kv = 0; kv < 16; ++kv) {
        const int cur = kv & 1;
        if (kv < 15) {
            const int j0n = (kv + 1) * 64;
            int r = sr0;
            int c = sc_lo ^ (r & 7);
            __builtin_amdgcn_global_load_lds(
                (const gbl_t*)(Ktile + (size_t)(j0n + r) * 64 + c * 8),
                (lds_t*)(&Ks[cur ^ 1][0] + w * 512), 16, 0, 0);
            __builtin_amdgcn_global_load_lds(
                (const gbl_t*)(Vtile + (size_t)r * 1024 + j0n + c * 8),
                (lds_t*)(&Vs[cur ^ 1][0] + w * 512), 16, 0, 0);
            if (tid < 192) {
                int rowi = j0n - qt * 128 + 896 + tid;
                rowi = (rowi < 2046) ? rowi : 2046;
                Bias2[cur ^ 1][tid] = rel_bias[(size_t)rowi * 16 + h] * LOG2E;
            }
        }

        const unsigned short* kbuf = &Ks[cur][0];
        f32x4 s[4];
        __builtin_amdgcn_s_setprio(1);
#pragma unroll
        for (int f = 0; f < 4; ++f) {
            int krow = f * 16 + lrow;
            int sw0 = (lgrp ^ (lrow & 7)) * 8;
            int sw1 = ((4 | lgrp) ^ (lrow & 7)) * 8;
            bf16x8 kb0 = *reinterpret_cast<const bf16x8*>(kbuf + krow * 64 + sw0);
            bf16x8 kb1 = *reinterpret_cast<const bf16x8*>(kbuf + krow * 64 + sw1);
            f32x4 z = {0.f, 0.f, 0.f, 0.f};
            z = MFMA16(kb0, qa0, z);
            z = MFMA16(kb1, qa1, z);
            s[f] = z;
        }
        __builtin_amdgcn_s_setprio(0);

        float x[4][4];
        float pm = -3.0e38f;
#pragma unroll
        for (int f = 0; f < 4; ++f)
#pragma unroll
            for (int r = 0; r < 4; ++r) {
                float xv = s[f][r] * SCALE2 + Bias2[cur][bbase + f * 16 + r];
                x[f][r] = xv;
                pm = fmaxf(pm, xv);
            }
        pm = fmaxf(pm, __shfl_xor(pm, 16));
        pm = fmaxf(pm, __shfl_xor(pm, 32));

        if (!__all(pm - m_run <= THR)) {
            float mnew = fmaxf(m_run, pm);
            float corr = __builtin_amdgcn_exp2f(m_run - mnew);
            m_run = mnew;
            l_run *= corr;
            float cb[4];
#pragma unroll
            for (int r = 0; r < 4; ++r) cb[r] = __shfl(corr, lgrp * 4 + r);
#pragma unroll
            for (int n = 0; n < 4; n++)
#pragma unroll
                for (int r = 0; r < 4; r++) o_acc[n][r] *= cb[r];
        }

        float su = 0.f;
#pragma unroll
        for (int f = 0; f < 4; ++f)
#pragma unroll
            for (int r = 0; r < 4; ++r) {
                float pv = __builtin_amdgcn_exp2f(x[f][r] - m_run);
                x[f][r] = pv;
                su += pv;
            }
        l_run += su;

#pragma unroll
        for (int f = 0; f < 4; ++f) {
            unsigned int plo, phi;
            asm("v_cvt_pk_bf16_f32 %0, %1, %2"
                : "=v"(plo)
                : "v"(x[f][0]), "v"(x[f][1]));
            asm("v_cvt_pk_bf16_f32 %0, %1, %2"
                : "=v"(phi)
                : "v"(x[f][2]), "v"(x[f][3]));
            const int chunk = (f * 2 + (lgrp >> 1)) ^ (lrow & 7);
            uint2 pw;
            pw.x = plo;
            pw.y = phi;
            *reinterpret_cast<uint2*>(
                &Ps[w][lrow * 64 + chunk * 8 + (lgrp & 1) * 4]) = pw;
        }

        const unsigned short* vbuf = &Vs[cur][0];
        __builtin_amdgcn_s_setprio(1);
#pragma unroll
        for (int jc = 0; jc < 2; ++jc) {
            int pc = ((4 * jc + lgrp) ^ (lrow & 7)) * 8;
            bf16x8 pa =
                *reinterpret_cast<const bf16x8*>(&Ps[w][0] + lrow * 64 + pc);
#pragma unroll
            for (int n = 0; n < 4; n++) {
                int vrow = n * 16 + lrow;
                bf16x8 vb =
                    *reinterpret_cast<const bf16x8*>(vbuf + vrow * 64 + pc);
                o_acc[n] = MFMA16(pa, vb, o_acc[n]);
            }
        }
        __builtin_amdgcn_s_setprio(0);

        if (kv < 15) {
            asm volatile("s_waitcnt vmcnt(0)" ::: "memory");
            __syncthreads();
        }
    }

    float lt = l_run + __shfl_xor(l_run, 16);
    lt += __shfl_xor(lt, 32);
    float rl[4];
#pragma unroll
    for (int r = 0; r < 4; ++r) rl[r] = 1.0f / __shfl(lt, lgrp * 4 + r);

    // compact hi-only epilogue
#pragma unroll
    for (int n = 0; n < 4; n++) {
#pragma unroll
        for (int r = 0; r < 4; r++) {
            float val = o_acc[n][r] * rl[r];
            int ia = qt * 128 + w * 16 + lgrp * 4 + r;
            size_t m = (size_t)b * 1024 + ia;
            int col = h * 64 + n * 16 + lrow;
            A3[m * 1024 + col] = f2bf(val);
        }
    }
}

extern "C" void kernel_launch(void* const* d_in, const int* in_sizes, int n_in,
                              void* d_out, int out_size, void* d_ws,
                              size_t ws_size, hipStream_t stream) {
    const float* x = (const float*)d_in[0];
    const float* w_qkv = (const float*)d_in[1];
    const float* w_out = (const float*)d_in[2];
    const float* rel_bias = (const float*)d_in[3];
    float* out = (float*)d_out;

    char* ws = (char*)d_ws;
    size_t off = 0;
    auto alloc = [&](size_t bytes) {
        char* p = ws + off;
        off += (bytes + 255) & ~(size_t)255;
        return p;
    };
    unsigned short* A1h = (unsigned short*)alloc((size_t)4096 * 1024 * 2);
    unsigned short* W1h = (unsigned short*)alloc((size_t)3072 * 1024 * 2);
    unsigned short* Qb = (unsigned short*)alloc((size_t)64 * 1024 * 64 * 2);
    unsigned short* Kb = (unsigned short*)alloc((size_t)64 * 1024 * 64 * 2);
    unsigned short* Vb = (unsigned short*)alloc((size_t)64 * 1024 * 64 * 2);
    unsigned short* A3h = (unsigned short*)alloc((size_t)4096 * 1024 * 2);
    unsigned short* W3h = (unsigned short*)alloc((size_t)1024 * 1024 * 2);
    // V^T aliases A1h (8 MB each): A1h dead after gemm256_hi; transpose_v after.
    unsigned short* Vtg = A1h;

    hipLaunchKernelGGL(prep_all, dim3(2048), dim3(256), 0, stream, x, w_qkv,
                       w_out, A1h, W1h, W3h);
    hipLaunchKernelGGL(gemm256_hi, dim3(12, 16), dim3(512), 0, stream, A1h, W1h,
                       Qb, Kb, Vb);
    hipLaunchKernelGGL(transpose_v, dim3(16, 64), dim3(256), 0, stream, Vb, Vtg);
    hipLaunchKernelGGL(attn_kernel, dim3(8, 64), dim3(512), 0, stream, Qb, Kb,
                       Vtg, rel_bias, A3h);
    hipLaunchKernelGGL(gemm_out_v4, dim3(512), dim3(256), 0, stream, A3h, W3h,
                       out);
}

// Round 16
// 105.180 us; speedup vs baseline: 1.8485x; 1.0323x over previous
//
#include <hip/hip_runtime.h>
#include <hip/hip_bf16.h>

typedef short bf16x8 __attribute__((ext_vector_type(8)));
typedef float f32x4  __attribute__((ext_vector_type(4)));

typedef __attribute__((address_space(3))) void lds_t;
typedef __attribute__((address_space(1))) void gbl_t;

#define MFMA16(a,b,c) __builtin_amdgcn_mfma_f32_16x16x32_bf16((a),(b),(c),0,0,0)

__device__ __forceinline__ unsigned short f2bf(float f) {
    __hip_bfloat16 h = __float2bfloat16(f);
    return __builtin_bit_cast(unsigned short, h);
}
__device__ __forceinline__ float bf2f(unsigned short u) {
    __hip_bfloat16 h = __builtin_bit_cast(__hip_bfloat16, u);
    return __bfloat162float(h);
}

// ============================================================================
// Fused prep (R15, unchanged): x -> A1h, w_qkv (einops permute) -> W1h,
// w_out -> W3h.  All bf16 hi-only compact, float4-vectorized, grid-stride.
// ============================================================================
__global__ void prep_all(const float* __restrict__ x,
                         const float* __restrict__ w_qkv,
                         const float* __restrict__ w_out,
                         unsigned short* __restrict__ A1h,
                         unsigned short* __restrict__ W1h,
                         unsigned short* __restrict__ W3h) {
    const int NX = 4096 * 256, NW1 = 3072 * 256, NW3 = 1024 * 256;
    for (int idx = blockIdx.x * blockDim.x + threadIdx.x; idx < NX + NW1 + NW3;
         idx += gridDim.x * blockDim.x) {
        if (idx < NX) {
            int base = idx * 4;
            float4 v = *reinterpret_cast<const float4*>(x + base);
            ushort4 hi;
            hi.x = f2bf(v.x); hi.y = f2bf(v.y);
            hi.z = f2bf(v.z); hi.w = f2bf(v.w);
            *reinterpret_cast<ushort4*>(A1h + base) = hi;
        } else if (idx < NX + NW1) {
            int base = (idx - NX) * 4;
            int n = base >> 10, c = base & 1023;
            int d = n & 63, which = n >> 10, h = (n >> 6) & 15;
            int srow = d * 48 + which * 16 + h;
            float4 v =
                *reinterpret_cast<const float4*>(w_qkv + (size_t)srow * 1024 + c);
            ushort4 hi;
            hi.x = f2bf(v.x); hi.y = f2bf(v.y);
            hi.z = f2bf(v.z); hi.w = f2bf(v.w);
            *reinterpret_cast<ushort4*>(W1h + (size_t)n * 1024 + c) = hi;
        } else {
            int base = (idx - NX - NW1) * 4;
            float4 v = *reinterpret_cast<const float4*>(w_out + base);
            ushort4 hi;
            hi.x = f2bf(v.x); hi.y = f2bf(v.y);
            hi.z = f2bf(v.z); hi.w = f2bf(v.w);
            *reinterpret_cast<ushort4*>(W3h + base) = hi;
        }
    }
}

// ============================================================================
// 256x256 hi-only bf16 GEMM for QKV — exact R10/R15 structure (measured best
// ~33us).  grid (12,16), 8 waves (2Mx4N), wave tile 128x64, acc[8][4],
// 4-slot ring, depth-2, counted vmcnt(4), XOR swizzle (0 conflicts).
// ============================================================================
__global__ __launch_bounds__(512, 2) void gemm256_hi(
    const unsigned short* __restrict__ A, const unsigned short* __restrict__ B,
    unsigned short* __restrict__ outQ, unsigned short* __restrict__ outK,
    unsigned short* __restrict__ outV) {
    __shared__ unsigned short lds[65536];  // A ring [0,32768), B ring [32768,65536)
    const int tid = threadIdx.x;
    const int wid = tid >> 6, lane = tid & 63;
    const int lrow = lane & 15, lgrp = lane >> 4;
    const int wr = wid >> 2, wc = wid & 3;
    const int mtile = blockIdx.y * 256, ntile = blockIdx.x * 256;

    const int csw = lgrp ^ ((lrow >> 1) & 3);
    const int aoff = (wr * 128 + lrow) * 32 + csw * 8;
    const int boff = 32768 + (wc * 64 + lrow) * 32 + csw * 8;

    const int sreg = wid * 2;
    const int srow0 = sreg * 16 + (lane >> 2);
    const int srow1 = (sreg + 1) * 16 + (lane >> 2);
    const int schunk = (lane & 3) ^ ((lane >> 3) & 3);
    const int sdst0 = sreg * 512;

    f32x4 acc[8][4];
#pragma unroll
    for (int i = 0; i < 8; ++i)
#pragma unroll
        for (int j = 0; j < 4; ++j) {
            f32x4 z = {0.f, 0.f, 0.f, 0.f};
            acc[i][j] = z;
        }

#pragma unroll
    for (int s0 = 0; s0 < 2; ++s0) {
        const int kb = s0 * 32;
        __builtin_amdgcn_global_load_lds(
            (const gbl_t*)(A + (size_t)(mtile + srow0) * 1024 + kb + schunk * 8),
            (lds_t*)(lds + s0 * 8192 + sdst0), 16, 0, 0);
        __builtin_amdgcn_global_load_lds(
            (const gbl_t*)(A + (size_t)(mtile + srow1) * 1024 + kb + schunk * 8),
            (lds_t*)(lds + s0 * 8192 + sdst0 + 512), 16, 0, 0);
        __builtin_amdgcn_global_load_lds(
            (const gbl_t*)(B + (size_t)(ntile + srow0) * 1024 + kb + schunk * 8),
            (lds_t*)(lds + 32768 + s0 * 8192 + sdst0), 16, 0, 0);
        __builtin_amdgcn_global_load_lds(
            (const gbl_t*)(B + (size_t)(ntile + srow1) * 1024 + kb + schunk * 8),
            (lds_t*)(lds + 32768 + s0 * 8192 + sdst0 + 512), 16, 0, 0);
    }
    asm volatile("s_waitcnt vmcnt(4)" ::: "memory");
    __syncthreads();

    for (int s = 0; s < 32; ++s) {
        const int sa = s & 3;
        const unsigned short* sbase = lds + sa * 8192;

        bf16x8 af[8];
#pragma unroll
        for (int i = 0; i < 8; ++i)
            af[i] = *reinterpret_cast<const bf16x8*>(sbase + aoff + i * 512);
        bf16x8 b0 = *reinterpret_cast<const bf16x8*>(sbase + boff);
        bf16x8 b1 = *reinterpret_cast<const bf16x8*>(sbase + boff + 512);

        if (s <= 29) {
            const int kb2 = (s + 2) * 32;
            const int s2 = (s + 2) & 3;
            __builtin_amdgcn_global_load_lds(
                (const gbl_t*)(A + (size_t)(mtile + srow0) * 1024 + kb2 + schunk * 8),
                (lds_t*)(lds + s2 * 8192 + sdst0), 16, 0, 0);
            __builtin_amdgcn_global_load_lds(
                (const gbl_t*)(A + (size_t)(mtile + srow1) * 1024 + kb2 + schunk * 8),
                (lds_t*)(lds + s2 * 8192 + sdst0 + 512), 16, 0, 0);
        }
        __builtin_amdgcn_s_setprio(1);
#pragma unroll
        for (int i = 0; i < 8; ++i) {
            acc[i][0] = MFMA16(af[i], b0, acc[i][0]);
            acc[i][1] = MFMA16(af[i], b1, acc[i][1]);
        }
        __builtin_amdgcn_s_setprio(0);

        bf16x8 b2 = *reinterpret_cast<const bf16x8*>(sbase + boff + 1024);
        bf16x8 b3 = *reinterpret_cast<const bf16x8*>(sbase + boff + 1536);
        if (s <= 29) {
            const int kb2 = (s + 2) * 32;
            const int s2 = (s + 2) & 3;
            __builtin_amdgcn_global_load_lds(
                (const gbl_t*)(B + (size_t)(ntile + srow0) * 1024 + kb2 + schunk * 8),
                (lds_t*)(lds + 32768 + s2 * 8192 + sdst0), 16, 0, 0);
            __builtin_amdgcn_global_load_lds(
                (const gbl_t*)(B + (size_t)(ntile + srow1) * 1024 + kb2 + schunk * 8),
                (lds_t*)(lds + 32768 + s2 * 8192 + sdst0 + 512), 16, 0, 0);
        }
        __builtin_amdgcn_s_setprio(1);
#pragma unroll
        for (int i = 0; i < 8; ++i) {
            acc[i][2] = MFMA16(af[i], b2, acc[i][2]);
            acc[i][3] = MFMA16(af[i], b3, acc[i][3]);
        }
        __builtin_amdgcn_s_setprio(0);

        if (s < 31) {
            if (s <= 29)
                asm volatile("s_waitcnt vmcnt(4)" ::: "memory");
            else
                asm volatile("s_waitcnt vmcnt(0)" ::: "memory");
            __syncthreads();
        }
    }

#pragma unroll
    for (int i = 0; i < 8; ++i) {
#pragma unroll
        for (int j = 0; j < 4; ++j) {
#pragma unroll
            for (int r = 0; r < 4; ++r) {
                float v = acc[i][j][r];
                int m = mtile + wr * 128 + i * 16 + lgrp * 4 + r;
                int n = ntile + wc * 64 + j * 16 + lrow;
                int which = n >> 10;
                int hh = (n >> 6) & 15;
                int d = n & 63;
                int b = m >> 10, t = m & 1023;
                unsigned short* dstp =
                    (which == 0) ? outQ : ((which == 1) ? outK : outV);
                dstp[((size_t)((b << 4) + hh) * 1024 + t) * 64 + d] = f2bf(v);
            }
        }
    }
}

// ============================================================================
// Out-projection GEMM v5 (R16): BK 32 -> 64, halving step count at constant
// MFMA work (R10/R11 evidence: per-step cost ~fixed, so time ~ steps*const;
// R11's halved-work/step regressed 45% -> converse: doubled work/step wins).
// 16 steps of 16 MFMA/wave (2 K-subfrags).  Tile 64x128, 4 waves (2Mx2N),
// wave 32x64, acc[2][4].  2-slot dbuf: As 2x8KB + Bs 2x16KB = 48KB -> still
// 3 blocks/CU.  64-col rows: 8-chunk XOR swizzle chunk^=(row&7), both-sides
// (linear LDS dest, pre-swizzled source, swizzled ds_read).  XCD swizzle.
// ============================================================================
__global__ __launch_bounds__(256, 3) void gemm_out_v5(
    const unsigned short* __restrict__ A, const unsigned short* __restrict__ B,
    float* __restrict__ outF) {
    __shared__ unsigned short As[2][64 * 64];   // 16 KB
    __shared__ unsigned short Bs[2][128 * 64];  // 32 KB
    const int tid = threadIdx.x;
    const int wid = tid >> 6, lane = tid & 63;
    const int lrow = lane & 15, lgrp = lane >> 4;
    const int wr = wid >> 1, wc = wid & 1;
    const int h = blockIdx.x;
    const int xcd = h & 7, within = h >> 3;
    const int mtile = (xcd * 8 + (within & 7)) * 64;
    const int ntile = (within >> 3) * 128;

    // staging: thread covers 16B at LDS linear (tid*8 shorts) per 4KB chunk.
    // row = e*32 + (tid>>3), lds chunk = tid&7; source col chunk pre-swizzled.
    const int srow = tid >> 3;                  // 0..31
    const int schunk = (tid & 7) ^ (srow & 7);  // inverse-swizzled source chunk
    const unsigned short* Abase = A + (size_t)(mtile + srow) * 1024 + schunk * 8;
    const unsigned short* Bbase = B + (size_t)(ntile + srow) * 1024 + schunk * 8;

    // read offsets (shorts): row*64 + ((k*4+lgrp)^(lrow&7))*8
    const int csw0 = (lgrp ^ (lrow & 7)) * 8;        // ksub 0
    const int csw1 = ((4 | lgrp) ^ (lrow & 7)) * 8;  // ksub 1
    const int arow = wr * 32 + lrow;                 // + i*16
    const int brow = wc * 64 + lrow;                 // + j*16

    f32x4 acc[2][4];
#pragma unroll
    for (int i = 0; i < 2; ++i)
#pragma unroll
        for (int j = 0; j < 4; ++j) {
            f32x4 z = {0.f, 0.f, 0.f, 0.f};
            acc[i][j] = z;
        }

    // prologue: stage slot 0 (kb = 0): A rows 0..63 (2x), B rows 0..127 (4x)
#pragma unroll
    for (int e = 0; e < 2; ++e)
        __builtin_amdgcn_global_load_lds(
            (const gbl_t*)(Abase + (size_t)e * 32 * 1024),
            (lds_t*)(&As[0][0] + e * 2048 + tid * 8), 16, 0, 0);
#pragma unroll
    for (int e = 0; e < 4; ++e)
        __builtin_amdgcn_global_load_lds(
            (const gbl_t*)(Bbase + (size_t)e * 32 * 1024),
            (lds_t*)(&Bs[0][0] + e * 2048 + tid * 8), 16, 0, 0);
    asm volatile("s_waitcnt vmcnt(0)" ::: "memory");
    __syncthreads();

    for (int s = 0; s < 16; ++s) {
        const int cur = s & 1;
        if (s < 15) {
            const int kb = (s + 1) * 64;
            const int nx = cur ^ 1;
#pragma unroll
            for (int e = 0; e < 2; ++e)
                __builtin_amdgcn_global_load_lds(
                    (const gbl_t*)(Abase + (size_t)e * 32 * 1024 + kb),
                    (lds_t*)(&As[nx][0] + e * 2048 + tid * 8), 16, 0, 0);
#pragma unroll
            for (int e = 0; e < 4; ++e)
                __builtin_amdgcn_global_load_lds(
                    (const gbl_t*)(Bbase + (size_t)e * 32 * 1024 + kb),
                    (lds_t*)(&Bs[nx][0] + e * 2048 + tid * 8), 16, 0, 0);
        }
        bf16x8 a0[2], a1[2], b0[4], b1[4];
#pragma unroll
        for (int i = 0; i < 2; ++i) {
            a0[i] = *reinterpret_cast<const bf16x8*>(&As[cur][0] +
                                                     (arow + i * 16) * 64 + csw0);
            a1[i] = *reinterpret_cast<const bf16x8*>(&As[cur][0] +
                                                     (arow + i * 16) * 64 + csw1);
        }
#pragma unroll
        for (int j = 0; j < 4; ++j) {
            b0[j] = *reinterpret_cast<const bf16x8*>(&Bs[cur][0] +
                                                     (brow + j * 16) * 64 + csw0);
            b1[j] = *reinterpret_cast<const bf16x8*>(&Bs[cur][0] +
                                                     (brow + j * 16) * 64 + csw1);
        }
        __builtin_amdgcn_s_setprio(1);
#pragma unroll
        for (int i = 0; i < 2; ++i)
#pragma unroll
            for (int j = 0; j < 4; ++j) {
                acc[i][j] = MFMA16(a0[i], b0[j], acc[i][j]);
                acc[i][j] = MFMA16(a1[i], b1[j], acc[i][j]);
            }
        __builtin_amdgcn_s_setprio(0);
        if (s < 15) {
            asm volatile("s_waitcnt vmcnt(0)" ::: "memory");
            __syncthreads();
        }
    }

#pragma unroll
    for (int i = 0; i < 2; ++i)
#pragma unroll
        for (int j = 0; j < 4; ++j)
#pragma unroll
            for (int r = 0; r < 4; ++r) {
                int m = mtile + wr * 32 + i * 16 + lgrp * 4 + r;
                int n = ntile + wc * 64 + j * 16 + lrow;
                outF[(size_t)m * 1024 + n] = acc[i][j][r];
            }
}

// V [bh][1024][64] -> V^T [bh][64][1024], LDS-tiled, coalesced both sides.
__global__ __launch_bounds__(256) void transpose_v(
    const unsigned short* __restrict__ Vb, unsigned short* __restrict__ Vtg) {
    __shared__ unsigned short L[64][72];
    const int tt = blockIdx.x, bh = blockIdx.y;
    const int tid = threadIdx.x;
#pragma unroll
    for (int e = 0; e < 2; ++e) {
        int chunk = e * 256 + tid;
        int r = chunk >> 3, c = (chunk & 7) * 8;
        uint4 v = *reinterpret_cast<const uint4*>(
            Vb + ((size_t)bh * 1024 + tt * 64 + r) * 64 + c);
        *reinterpret_cast<uint4*>(&L[r][c]) = v;
    }
    __syncthreads();
#pragma unroll
    for (int e = 0; e < 2; ++e) {
        int chunk = e * 256 + tid;
        int d = chunk >> 3, t0 = (chunk & 7) * 8;
        unsigned short tmp[8];
#pragma unroll
        for (int u = 0; u < 8; ++u) tmp[u] = L[t0 + u][d];
        *reinterpret_cast<uint4*>(Vtg + ((size_t)bh * 64 + d) * 1024 + tt * 64 +
                                  t0) = *reinterpret_cast<const uint4*>(tmp);
    }
}

// ============================================================================
// Flash attention — R10 structure + R16 one-time bias stage (the correct
// half of R13): full 1151-float strip staged once, per-tile tid<192 loads
// and divergent branch removed.  K/V LDS dbuf staging KEPT (R13 lesson:
// staging is the prefetch pipeline; K/V don't fit L1).
// QBLK=128, 8 waves, swapped QK^T, exp2 softmax, defer-max, cvt_pk P-pack.
// LDS 52.6KB -> 3 blocks/CU (unchanged).
// ============================================================================
__global__ __launch_bounds__(512) void attn_kernel(
    const unsigned short* __restrict__ Qb, const unsigned short* __restrict__ Kb,
    const unsigned short* __restrict__ Vtg, const float* __restrict__ rel_bias,
    unsigned short* __restrict__ A3) {
    const int qt = blockIdx.x;  // 0..7 (128 q-rows each)
    const int bh = blockIdx.y;  // 0..63
    const int b = bh >> 4, h = bh & 15;
    const int tid = threadIdx.x;
    const int w = tid >> 6, lane = tid & 63;  // w in 0..7
    const int lrow = lane & 15, lgrp = lane >> 4;
    const float LOG2E = 1.4426950408889634f;
    const float SCALE2 = 0.125f * 1.4426950408889634f;
    const float THR = 11.5f;  // ~8 nats in exp2 units

    __shared__ unsigned short Ks[2][64 * 64];  // 16 KB
    __shared__ unsigned short Vs[2][64 * 64];  // 16 KB
    __shared__ unsigned short Ps[8][16 * 64];  // 16 KB
    __shared__ float BiasF[1152];              // 4.5 KB, staged once

    const unsigned short* Ktile = Kb + (size_t)bh * 1024 * 64;
    const unsigned short* Vtile = Vtg + (size_t)bh * 64 * 1024;

    const unsigned short* Qp =
        Qb + ((size_t)bh * 1024 + qt * 128 + w * 16 + lrow) * 64;
    bf16x8 qa0 = *reinterpret_cast<const bf16x8*>(Qp + lgrp * 8);
    bf16x8 qa1 = *reinterpret_cast<const bf16x8*>(Qp + 32 + lgrp * 8);

    const int sr0 = w * 8 + (lane >> 3);
    const int sc_lo = lane & 7;

    float m_run = -3.0e38f;
    float l_run = 0.f;
    f32x4 o_acc[4];
#pragma unroll
    for (int n = 0; n < 4; n++) {
        f32x4 z = {0.f, 0.f, 0.f, 0.f};
        o_acc[n] = z;
    }

    // BiasF[v] for v = j - (i - qt*128) + 127 in [0,1150]; rel row = v + rbase,
    // rbase = 896 - qt*128 in [0,896]; max index 2046 -> in bounds.
    const int bbase = lgrp * 4 + 127 - w * 16 - lrow;

    {
        {
            int r = sr0;
            int c = sc_lo ^ (r & 7);
            __builtin_amdgcn_global_load_lds(
                (const gbl_t*)(Ktile + (size_t)r * 64 + c * 8),
                (lds_t*)(&Ks[0][0] + w * 512), 16, 0, 0);
            __builtin_amdgcn_global_load_lds(
                (const gbl_t*)(Vtile + (size_t)r * 1024 + c * 8),
                (lds_t*)(&Vs[0][0] + w * 512), 16, 0, 0);
        }
        const int rbase = 896 - qt * 128;
        for (int t = tid; t < 1151; t += 512)
            BiasF[t] = rel_bias[(size_t)(t + rbase) * 16 + h] * LOG2E;
        asm volatile("s_waitcnt vmcnt(0)" ::: "memory");
        __syncthreads();
    }

    for (int kv = 0; kv < 16; ++kv) {
        const int cur = kv & 1;
        const int j0 = kv * 64;
        if (kv < 15) {
            const int j0n = (kv + 1) * 64;
            int r = sr0;
            int c = sc_lo ^ (r & 7);
            __builtin_amdgcn_global_load_lds(
                (const gbl_t*)(Ktile + (size_t)(j0n + r) * 64 + c * 8),
                (lds_t*)(&Ks[cur ^ 1][0] + w * 512), 16, 0, 0);
            __builtin_amdgcn_global_load_lds(
                (const gbl_t*)(Vtile + (size_t)r * 1024 + j0n + c * 8),
                (lds_t*)(&Vs[cur ^ 1][0] + w * 512), 16, 0, 0);
        }

        const unsigned short* kbuf = &Ks[cur][0];
        f32x4 s[4];
        __builtin_amdgcn_s_setprio(1);
#pragma unroll
        for (int f = 0; f < 4; ++f) {
            int krow = f * 16 + lrow;
            int sw0 = (lgrp ^ (lrow & 7)) * 8;
            int sw1 = ((4 | lgrp) ^ (lrow & 7)) * 8;
            bf16x8 kb0 = *reinterpret_cast<const bf16x8*>(kbuf + krow * 64 + sw0);
            bf16x8 kb1 = *reinterpret_cast<const bf16x8*>(kbuf + krow * 64 + sw1);
            f32x4 z = {0.f, 0.f, 0.f, 0.f};
            z = MFMA16(kb0, qa0, z);
            z = MFMA16(kb1, qa1, z);
            s[f] = z;
        }
        __builtin_amdgcn_s_setprio(0);

        float x[4][4];
        float pm = -3.0e38f;
#pragma unroll
        for (int f = 0; f < 4; ++f)
#pragma unroll
            for (int r = 0; r < 4; ++r) {
                float xv = s[f][r] * SCALE2 + BiasF[j0 + bbase + f * 16 + r];
                x[f][r] = xv;
                pm = fmaxf(pm, xv);
            }
        pm = fmaxf(pm, __shfl_xor(pm, 16));
        pm = fmaxf(pm, __shfl_xor(pm, 32));

        if (!__all(pm - m_run <= THR)) {
            float mnew = fmaxf(m_run, pm);
            float corr = __builtin_amdgcn_exp2f(m_run - mnew);
            m_run = mnew;
            l_run *= corr;
            float cb[4];
#pragma unroll
            for (int r = 0; r < 4; ++r) cb[r] = __shfl(corr, lgrp * 4 + r);
#pragma unroll
            for (int n = 0; n < 4; n++)
#pragma unroll
                for (int r = 0; r < 4; r++) o_acc[n][r] *= cb[r];
        }

        float su = 0.f;
#pragma unroll
        for (int f = 0; f < 4; ++f)
#pragma unroll
            for (int r = 0; r < 4; ++r) {
                float pv = __builtin_amdgcn_exp2f(x[f][r] - m_run);
                x[f][r] = pv;
                su += pv;
            }
        l_run += su;

#pragma unroll
        for (int f = 0; f < 4; ++f) {
            unsigned int plo, phi;
            asm("v_cvt_pk_bf16_f32 %0, %1, %2"
                : "=v"(plo)
                : "v"(x[f][0]), "v"(x[f][1]));
            asm("v_cvt_pk_bf16_f32 %0, %1, %2"
                : "=v"(phi)
                : "v"(x[f][2]), "v"(x[f][3]));
            const int chunk = (f * 2 + (lgrp >> 1)) ^ (lrow & 7);
            uint2 pw;
            pw.x = plo;
            pw.y = phi;
            *reinterpret_cast<uint2*>(
                &Ps[w][lrow * 64 + chunk * 8 + (lgrp & 1) * 4]) = pw;
        }

        const unsigned short* vbuf = &Vs[cur][0];
        __builtin_amdgcn_s_setprio(1);
#pragma unroll
        for (int jc = 0; jc < 2; ++jc) {
            int pc = ((4 * jc + lgrp) ^ (lrow & 7)) * 8;
            bf16x8 pa =
                *reinterpret_cast<const bf16x8*>(&Ps[w][0] + lrow * 64 + pc);
#pragma unroll
            for (int n = 0; n < 4; n++) {
                int vrow = n * 16 + lrow;
                bf16x8 vb =
                    *reinterpret_cast<const bf16x8*>(vbuf + vrow * 64 + pc);
                o_acc[n] = MFMA16(pa, vb, o_acc[n]);
            }
        }
        __builtin_amdgcn_s_setprio(0);

        if (kv < 15) {
            asm volatile("s_waitcnt vmcnt(0)" ::: "memory");
            __syncthreads();
        }
    }

    float lt = l_run + __shfl_xor(l_run, 16);
    lt += __shfl_xor(lt, 32);
    float rl[4];
#pragma unroll
    for (int r = 0; r < 4; ++r) rl[r] = 1.0f / __shfl(lt, lgrp * 4 + r);

    // compact hi-only epilogue
#pragma unroll
    for (int n = 0; n < 4; n++) {
#pragma unroll
        for (int r = 0; r < 4; r++) {
            float val = o_acc[n][r] * rl[r];
            int ia = qt * 128 + w * 16 + lgrp * 4 + r;
            size_t m = (size_t)b * 1024 + ia;
            int col = h * 64 + n * 16 + lrow;
            A3[m * 1024 + col] = f2bf(val);
        }
    }
}

extern "C" void kernel_launch(void* const* d_in, const int* in_sizes, int n_in,
                              void* d_out, int out_size, void* d_ws,
                              size_t ws_size, hipStream_t stream) {
    const float* x = (const float*)d_in[0];
    const float* w_qkv = (const float*)d_in[1];
    const float* w_out = (const float*)d_in[2];
    const float* rel_bias = (const float*)d_in[3];
    float* out = (float*)d_out;

    char* ws = (char*)d_ws;
    size_t off = 0;
    auto alloc = [&](size_t bytes) {
        char* p = ws + off;
        off += (bytes + 255) & ~(size_t)255;
        return p;
    };
    unsigned short* A1h = (unsigned short*)alloc((size_t)4096 * 1024 * 2);
    unsigned short* W1h = (unsigned short*)alloc((size_t)3072 * 1024 * 2);
    unsigned short* Qb = (unsigned short*)alloc((size_t)64 * 1024 * 64 * 2);
    unsigned short* Kb = (unsigned short*)alloc((size_t)64 * 1024 * 64 * 2);
    unsigned short* Vb = (unsigned short*)alloc((size_t)64 * 1024 * 64 * 2);
    unsigned short* A3h = (unsigned short*)alloc((size_t)4096 * 1024 * 2);
    unsigned short* W3h = (unsigned short*)alloc((size_t)1024 * 1024 * 2);
    // V^T aliases A1h (8 MB each): A1h dead after gemm256_hi; transpose_v after.
    unsigned short* Vtg = A1h;

    hipLaunchKernelGGL(prep_all, dim3(2048), dim3(256), 0, stream, x, w_qkv,
                       w_out, A1h, W1h, W3h);
    hipLaunchKernelGGL(gemm256_hi, dim3(12, 16), dim3(512), 0, stream, A1h, W1h,
                       Qb, Kb, Vb);
    hipLaunchKernelGGL(transpose_v, dim3(16, 64), dim3(256), 0, stream, Vb, Vtg);
    hipLaunchKernelGGL(attn_kernel, dim3(8, 64), dim3(512), 0, stream, Qb, Kb,
                       Vtg, rel_bias, A3h);
    hipLaunchKernelGGL(gemm_out_v5, dim3(512), dim3(256), 0, stream, A3h, W3h,
                       out);
}

// Round 17
// 101.187 us; speedup vs baseline: 1.9215x; 1.0395x over previous
//
#include <hip/hip_runtime.h>
#include <hip/hip_bf16.h>

typedef short bf16x8 __attribute__((ext_vector_type(8)));
typedef float f32x4  __attribute__((ext_vector_type(4)));

typedef __attribute__((address_space(3))) void lds_t;
typedef __attribute__((address_space(1))) void gbl_t;

#define MFMA16(a,b,c) __builtin_amdgcn_mfma_f32_16x16x32_bf16((a),(b),(c),0,0,0)

__device__ __forceinline__ unsigned short f2bf(float f) {
    __hip_bfloat16 h = __float2bfloat16(f);
    return __builtin_bit_cast(unsigned short, h);
}
__device__ __forceinline__ float bf2f(unsigned short u) {
    __hip_bfloat16 h = __builtin_bit_cast(__hip_bfloat16, u);
    return __bfloat162float(h);
}

// ============================================================================
// Fused prep (R15, unchanged): x -> A1h, w_qkv (einops permute) -> W1h,
// w_out -> W3h.  All bf16 hi-only compact, float4-vectorized, grid-stride.
// ============================================================================
__global__ void prep_all(const float* __restrict__ x,
                         const float* __restrict__ w_qkv,
                         const float* __restrict__ w_out,
                         unsigned short* __restrict__ A1h,
                         unsigned short* __restrict__ W1h,
                         unsigned short* __restrict__ W3h) {
    const int NX = 4096 * 256, NW1 = 3072 * 256, NW3 = 1024 * 256;
    for (int idx = blockIdx.x * blockDim.x + threadIdx.x; idx < NX + NW1 + NW3;
         idx += gridDim.x * blockDim.x) {
        if (idx < NX) {
            int base = idx * 4;
            float4 v = *reinterpret_cast<const float4*>(x + base);
            ushort4 hi;
            hi.x = f2bf(v.x); hi.y = f2bf(v.y);
            hi.z = f2bf(v.z); hi.w = f2bf(v.w);
            *reinterpret_cast<ushort4*>(A1h + base) = hi;
        } else if (idx < NX + NW1) {
            int base = (idx - NX) * 4;
            int n = base >> 10, c = base & 1023;
            int d = n & 63, which = n >> 10, h = (n >> 6) & 15;
            int srow = d * 48 + which * 16 + h;
            float4 v =
                *reinterpret_cast<const float4*>(w_qkv + (size_t)srow * 1024 + c);
            ushort4 hi;
            hi.x = f2bf(v.x); hi.y = f2bf(v.y);
            hi.z = f2bf(v.z); hi.w = f2bf(v.w);
            *reinterpret_cast<ushort4*>(W1h + (size_t)n * 1024 + c) = hi;
        } else {
            int base = (idx - NX - NW1) * 4;
            float4 v = *reinterpret_cast<const float4*>(w_out + base);
            ushort4 hi;
            hi.x = f2bf(v.x); hi.y = f2bf(v.y);
            hi.z = f2bf(v.z); hi.w = f2bf(v.w);
            *reinterpret_cast<ushort4*>(W3h + base) = hi;
        }
    }
}

// ============================================================================
// QKV GEMM v6 (R17): BK 32 -> 64 on the R10 256x256 skeleton.  Scaling law
// (R11 vs R16): per-step cost ~fixed -> time ~ steps*const; halving steps at
// constant work won on gemm_out (20->14us), apply here.  16 steps, 64 MFMA/
// step/wave (2 K-subfrags).  LDS 128KB 2-slot dbuf -> 1 block/CU, which is
// ALREADY the reality (192 blocks / 256 CUs) - no co-residency lost, barrier
// count halves.  8-chunk XOR swizzle chunk^=(row&7) both-sides (v5-proven).
// Staging: 4 A-loads before ksub0 MFMA, 4 B-loads before ksub1 MFMA,
// drain vmcnt(0)+barrier per step (2-slot; counted-vs-drain neutral per R8).
// grid (12,16), 8 waves (2Mx4N), wave tile 128x64, acc[8][4].
// ============================================================================
__global__ __launch_bounds__(512, 1) void gemm256_hi(
    const unsigned short* __restrict__ A, const unsigned short* __restrict__ B,
    unsigned short* __restrict__ outQ, unsigned short* __restrict__ outK,
    unsigned short* __restrict__ outV) {
    // 128 KB: A slots @0,16384; B slots @32768,49152 (shorts)
    __shared__ unsigned short lds[65536];
    const int tid = threadIdx.x;
    const int wid = tid >> 6, lane = tid & 63;
    const int lrow = lane & 15, lgrp = lane >> 4;
    const int wr = wid >> 2, wc = wid & 3;
    const int mtile = blockIdx.y * 256, ntile = blockIdx.x * 256;

    // read offsets (row stride 64 shorts)
    const int csw0 = (lgrp ^ (lrow & 7)) * 8;        // ksub0: cols [kb, kb+32)
    const int csw1 = ((4 | lgrp) ^ (lrow & 7)) * 8;  // ksub1: cols [kb+32, kb+64)
    const int arowb = (wr * 128 + lrow) * 64;        // + i*1024
    const int browb = (wc * 64 + lrow) * 64;         // + j*1024

    // staging: thread covers 4 rows per operand (rows e*64 + srow), 16B each.
    // LDS linear (row, schunk) <- global (row, schunk ^ (row&7)); row&7=srow&7.
    const int srow = tid >> 3;   // 0..63
    const int schunk = tid & 7;  // LDS chunk slot
    const int gchunk = schunk ^ (srow & 7);
    const unsigned short* Abase = A + (size_t)(mtile + srow) * 1024 + gchunk * 8;
    const unsigned short* Bbase = B + (size_t)(ntile + srow) * 1024 + gchunk * 8;
    const int sdst = srow * 64 + schunk * 8;  // + e*4096, + slot base

    f32x4 acc[8][4];
#pragma unroll
    for (int i = 0; i < 8; ++i)
#pragma unroll
        for (int j = 0; j < 4; ++j) {
            f32x4 z = {0.f, 0.f, 0.f, 0.f};
            acc[i][j] = z;
        }

    // prologue: stage step 0 into slot 0
#pragma unroll
    for (int e = 0; e < 4; ++e)
        __builtin_amdgcn_global_load_lds(
            (const gbl_t*)(Abase + (size_t)e * 64 * 1024),
            (lds_t*)(lds + e * 4096 + sdst), 16, 0, 0);
#pragma unroll
    for (int e = 0; e < 4; ++e)
        __builtin_amdgcn_global_load_lds(
            (const gbl_t*)(Bbase + (size_t)e * 64 * 1024),
            (lds_t*)(lds + 32768 + e * 4096 + sdst), 16, 0, 0);
    asm volatile("s_waitcnt vmcnt(0)" ::: "memory");
    __syncthreads();

    for (int s = 0; s < 16; ++s) {
        const int cur = s & 1;
        const unsigned short* abuf = lds + cur * 16384;
        const unsigned short* bbuf = lds + 32768 + cur * 16384;
        const int nx = cur ^ 1;
        const int kb = (s + 1) * 64;

        // stage next A (overlaps ksub0 compute)
        if (s < 15) {
#pragma unroll
            for (int e = 0; e < 4; ++e)
                __builtin_amdgcn_global_load_lds(
                    (const gbl_t*)(Abase + (size_t)e * 64 * 1024 + kb),
                    (lds_t*)(lds + nx * 16384 + e * 4096 + sdst), 16, 0, 0);
        }
        // ---- ksub0 ----
        {
            bf16x8 af[8], bfv[4];
#pragma unroll
            for (int i = 0; i < 8; ++i)
                af[i] = *reinterpret_cast<const bf16x8*>(abuf + arowb + i * 1024 +
                                                         csw0);
#pragma unroll
            for (int j = 0; j < 4; ++j)
                bfv[j] = *reinterpret_cast<const bf16x8*>(bbuf + browb +
                                                          j * 1024 + csw0);
            __builtin_amdgcn_s_setprio(1);
#pragma unroll
            for (int i = 0; i < 8; ++i)
#pragma unroll
                for (int j = 0; j < 4; ++j)
                    acc[i][j] = MFMA16(af[i], bfv[j], acc[i][j]);
            __builtin_amdgcn_s_setprio(0);
        }
        // stage next B (overlaps ksub1 compute)
        if (s < 15) {
#pragma unroll
            for (int e = 0; e < 4; ++e)
                __builtin_amdgcn_global_load_lds(
                    (const gbl_t*)(Bbase + (size_t)e * 64 * 1024 + kb),
                    (lds_t*)(lds + 32768 + nx * 16384 + e * 4096 + sdst), 16, 0,
                    0);
        }
        // ---- ksub1 ----
        {
            bf16x8 af[8], bfv[4];
#pragma unroll
            for (int i = 0; i < 8; ++i)
                af[i] = *reinterpret_cast<const bf16x8*>(abuf + arowb + i * 1024 +
                                                         csw1);
#pragma unroll
            for (int j = 0; j < 4; ++j)
                bfv[j] = *reinterpret_cast<const bf16x8*>(bbuf + browb +
                                                          j * 1024 + csw1);
            __builtin_amdgcn_s_setprio(1);
#pragma unroll
            for (int i = 0; i < 8; ++i)
#pragma unroll
                for (int j = 0; j < 4; ++j)
                    acc[i][j] = MFMA16(af[i], bfv[j], acc[i][j]);
            __builtin_amdgcn_s_setprio(0);
        }

        if (s < 15) {
            asm volatile("s_waitcnt vmcnt(0)" ::: "memory");
            __syncthreads();
        }
    }

#pragma unroll
    for (int i = 0; i < 8; ++i) {
#pragma unroll
        for (int j = 0; j < 4; ++j) {
#pragma unroll
            for (int r = 0; r < 4; ++r) {
                float v = acc[i][j][r];
                int m = mtile + wr * 128 + i * 16 + lgrp * 4 + r;
                int n = ntile + wc * 64 + j * 16 + lrow;
                int which = n >> 10;
                int hh = (n >> 6) & 15;
                int d = n & 63;
                int b = m >> 10, t = m & 1023;
                unsigned short* dstp =
                    (which == 0) ? outQ : ((which == 1) ? outK : outV);
                dstp[((size_t)((b << 4) + hh) * 1024 + t) * 64 + d] = f2bf(v);
            }
        }
    }
}

// ============================================================================
// Out-projection GEMM v5 (R16, unchanged — measured ~14us): BK=64, 16 steps,
// tile 64x128, 4 waves, 2-slot dbuf 48KB, XOR swizzle, XCD swizzle.
// ============================================================================
__global__ __launch_bounds__(256, 3) void gemm_out_v5(
    const unsigned short* __restrict__ A, const unsigned short* __restrict__ B,
    float* __restrict__ outF) {
    __shared__ unsigned short As[2][64 * 64];   // 16 KB
    __shared__ unsigned short Bs[2][128 * 64];  // 32 KB
    const int tid = threadIdx.x;
    const int wid = tid >> 6, lane = tid & 63;
    const int lrow = lane & 15, lgrp = lane >> 4;
    const int wr = wid >> 1, wc = wid & 1;
    const int h = blockIdx.x;
    const int xcd = h & 7, within = h >> 3;
    const int mtile = (xcd * 8 + (within & 7)) * 64;
    const int ntile = (within >> 3) * 128;

    const int srow = tid >> 3;                  // 0..31
    const int schunk = (tid & 7) ^ (srow & 7);  // inverse-swizzled source chunk
    const unsigned short* Abase = A + (size_t)(mtile + srow) * 1024 + schunk * 8;
    const unsigned short* Bbase = B + (size_t)(ntile + srow) * 1024 + schunk * 8;

    const int csw0 = (lgrp ^ (lrow & 7)) * 8;
    const int csw1 = ((4 | lgrp) ^ (lrow & 7)) * 8;
    const int arow = wr * 32 + lrow;
    const int brow = wc * 64 + lrow;

    f32x4 acc[2][4];
#pragma unroll
    for (int i = 0; i < 2; ++i)
#pragma unroll
        for (int j = 0; j < 4; ++j) {
            f32x4 z = {0.f, 0.f, 0.f, 0.f};
            acc[i][j] = z;
        }

#pragma unroll
    for (int e = 0; e < 2; ++e)
        __builtin_amdgcn_global_load_lds(
            (const gbl_t*)(Abase + (size_t)e * 32 * 1024),
            (lds_t*)(&As[0][0] + e * 2048 + tid * 8), 16, 0, 0);
#pragma unroll
    for (int e = 0; e < 4; ++e)
        __builtin_amdgcn_global_load_lds(
            (const gbl_t*)(Bbase + (size_t)e * 32 * 1024),
            (lds_t*)(&Bs[0][0] + e * 2048 + tid * 8), 16, 0, 0);
    asm volatile("s_waitcnt vmcnt(0)" ::: "memory");
    __syncthreads();

    for (int s = 0; s < 16; ++s) {
        const int cur = s & 1;
        if (s < 15) {
            const int kb = (s + 1) * 64;
            const int nx = cur ^ 1;
#pragma unroll
            for (int e = 0; e < 2; ++e)
                __builtin_amdgcn_global_load_lds(
                    (const gbl_t*)(Abase + (size_t)e * 32 * 1024 + kb),
                    (lds_t*)(&As[nx][0] + e * 2048 + tid * 8), 16, 0, 0);
#pragma unroll
            for (int e = 0; e < 4; ++e)
                __builtin_amdgcn_global_load_lds(
                    (const gbl_t*)(Bbase + (size_t)e * 32 * 1024 + kb),
                    (lds_t*)(&Bs[nx][0] + e * 2048 + tid * 8), 16, 0, 0);
        }
        bf16x8 a0[2], a1[2], b0[4], b1[4];
#pragma unroll
        for (int i = 0; i < 2; ++i) {
            a0[i] = *reinterpret_cast<const bf16x8*>(&As[cur][0] +
                                                     (arow + i * 16) * 64 + csw0);
            a1[i] = *reinterpret_cast<const bf16x8*>(&As[cur][0] +
                                                     (arow + i * 16) * 64 + csw1);
        }
#pragma unroll
        for (int j = 0; j < 4; ++j) {
            b0[j] = *reinterpret_cast<const bf16x8*>(&Bs[cur][0] +
                                                     (brow + j * 16) * 64 + csw0);
            b1[j] = *reinterpret_cast<const bf16x8*>(&Bs[cur][0] +
                                                     (brow + j * 16) * 64 + csw1);
        }
        __builtin_amdgcn_s_setprio(1);
#pragma unroll
        for (int i = 0; i < 2; ++i)
#pragma unroll
            for (int j = 0; j < 4; ++j) {
                acc[i][j] = MFMA16(a0[i], b0[j], acc[i][j]);
                acc[i][j] = MFMA16(a1[i], b1[j], acc[i][j]);
            }
        __builtin_amdgcn_s_setprio(0);
        if (s < 15) {
            asm volatile("s_waitcnt vmcnt(0)" ::: "memory");
            __syncthreads();
        }
    }

#pragma unroll
    for (int i = 0; i < 2; ++i)
#pragma unroll
        for (int j = 0; j < 4; ++j)
#pragma unroll
            for (int r = 0; r < 4; ++r) {
                int m = mtile + wr * 32 + i * 16 + lgrp * 4 + r;
                int n = ntile + wc * 64 + j * 16 + lrow;
                outF[(size_t)m * 1024 + n] = acc[i][j][r];
            }
}

// V [bh][1024][64] -> V^T [bh][64][1024], LDS-tiled, coalesced both sides.
__global__ __launch_bounds__(256) void transpose_v(
    const unsigned short* __restrict__ Vb, unsigned short* __restrict__ Vtg) {
    __shared__ unsigned short L[64][72];
    const int tt = blockIdx.x, bh = blockIdx.y;
    const int tid = threadIdx.x;
#pragma unroll
    for (int e = 0; e < 2; ++e) {
        int chunk = e * 256 + tid;
        int r = chunk >> 3, c = (chunk & 7) * 8;
        uint4 v = *reinterpret_cast<const uint4*>(
            Vb + ((size_t)bh * 1024 + tt * 64 + r) * 64 + c);
        *reinterpret_cast<uint4*>(&L[r][c]) = v;
    }
    __syncthreads();
#pragma unroll
    for (int e = 0; e < 2; ++e) {
        int chunk = e * 256 + tid;
        int d = chunk >> 3, t0 = (chunk & 7) * 8;
        unsigned short tmp[8];
#pragma unroll
        for (int u = 0; u < 8; ++u) tmp[u] = L[t0 + u][d];
        *reinterpret_cast<uint4*>(Vtg + ((size_t)bh * 64 + d) * 1024 + tt * 64 +
                                  t0) = *reinterpret_cast<const uint4*>(tmp);
    }
}

// ============================================================================
// Flash attention (R16, unchanged): R10 structure + one-time bias stage.
// QBLK=128, 8 waves, swapped QK^T, exp2 softmax, defer-max, cvt_pk P-pack,
// K/V dbuf via global_load_lds, XOR swizzle.
// ============================================================================
__global__ __launch_bounds__(512) void attn_kernel(
    const unsigned short* __restrict__ Qb, const unsigned short* __restrict__ Kb,
    const unsigned short* __restrict__ Vtg, const float* __restrict__ rel_bias,
    unsigned short* __restrict__ A3) {
    const int qt = blockIdx.x;  // 0..7 (128 q-rows each)
    const int bh = blockIdx.y;  // 0..63
    const int b = bh >> 4, h = bh & 15;
    const int tid = threadIdx.x;
    const int w = tid >> 6, lane = tid & 63;  // w in 0..7
    const int lrow = lane & 15, lgrp = lane >> 4;
    const float LOG2E = 1.4426950408889634f;
    const float SCALE2 = 0.125f * 1.4426950408889634f;
    const float THR = 11.5f;  // ~8 nats in exp2 units

    __shared__ unsigned short Ks[2][64 * 64];  // 16 KB
    __shared__ unsigned short Vs[2][64 * 64];  // 16 KB
    __shared__ unsigned short Ps[8][16 * 64];  // 16 KB
    __shared__ float BiasF[1152];              // 4.5 KB, staged once

    const unsigned short* Ktile = Kb + (size_t)bh * 1024 * 64;
    const unsigned short* Vtile = Vtg + (size_t)bh * 64 * 1024;

    const unsigned short* Qp =
        Qb + ((size_t)bh * 1024 + qt * 128 + w * 16 + lrow) * 64;
    bf16x8 qa0 = *reinterpret_cast<const bf16x8*>(Qp + lgrp * 8);
    bf16x8 qa1 = *reinterpret_cast<const bf16x8*>(Qp + 32 + lgrp * 8);

    const int sr0 = w * 8 + (lane >> 3);
    const int sc_lo = lane & 7;

    float m_run = -3.0e38f;
    float l_run = 0.f;
    f32x4 o_acc[4];
#pragma unroll
    for (int n = 0; n < 4; n++) {
        f32x4 z = {0.f, 0.f, 0.f, 0.f};
        o_acc[n] = z;
    }

    const int bbase = lgrp * 4 + 127 - w * 16 - lrow;

    {
        {
            int r = sr0;
            int c = sc_lo ^ (r & 7);
            __builtin_amdgcn_global_load_lds(
                (const gbl_t*)(Ktile + (size_t)r * 64 + c * 8),
                (lds_t*)(&Ks[0][0] + w * 512), 16, 0, 0);
            __builtin_amdgcn_global_load_lds(
                (const gbl_t*)(Vtile + (size_t)r * 1024 + c * 8),
                (lds_t*)(&Vs[0][0] + w * 512), 16, 0, 0);
        }
        const int rbase = 896 - qt * 128;
        for (int t = tid; t < 1151; t += 512)
            BiasF[t] = rel_bias[(size_t)(t + rbase) * 16 + h] * LOG2E;
        asm volatile("s_waitcnt vmcnt(0)" ::: "memory");
        __syncthreads();
    }

    for (int kv = 0; kv < 16; ++kv) {
        const int cur = kv & 1;
        const int j0 = kv * 64;
        if (kv < 15) {
            const int j0n = (kv + 1) * 64;
            int r = sr0;
            int c = sc_lo ^ (r & 7);
            __builtin_amdgcn_global_load_lds(
                (const gbl_t*)(Ktile + (size_t)(j0n + r) * 64 + c * 8),
                (lds_t*)(&Ks[cur ^ 1][0] + w * 512), 16, 0, 0);
            __builtin_amdgcn_global_load_lds(
                (const gbl_t*)(Vtile + (size_t)r * 1024 + j0n + c * 8),
                (lds_t*)(&Vs[cur ^ 1][0] + w * 512), 16, 0, 0);
        }

        const unsigned short* kbuf = &Ks[cur][0];
        f32x4 s[4];
        __builtin_amdgcn_s_setprio(1);
#pragma unroll
        for (int f = 0; f < 4; ++f) {
            int krow = f * 16 + lrow;
            int sw0 = (lgrp ^ (lrow & 7)) * 8;
            int sw1 = ((4 | lgrp) ^ (lrow & 7)) * 8;
            bf16x8 kb0 = *reinterpret_cast<const bf16x8*>(kbuf + krow * 64 + sw0);
            bf16x8 kb1 = *reinterpret_cast<const bf16x8*>(kbuf + krow * 64 + sw1);
            f32x4 z = {0.f, 0.f, 0.f, 0.f};
            z = MFMA16(kb0, qa0, z);
            z = MFMA16(kb1, qa1, z);
            s[f] = z;
        }
        __builtin_amdgcn_s_setprio(0);

        float x[4][4];
        float pm = -3.0e38f;
#pragma unroll
        for (int f = 0; f < 4; ++f)
#pragma unroll
            for (int r = 0; r < 4; ++r) {
                float xv = s[f][r] * SCALE2 + BiasF[j0 + bbase + f * 16 + r];
                x[f][r] = xv;
                pm = fmaxf(pm, xv);
            }
        pm = fmaxf(pm, __shfl_xor(pm, 16));
        pm = fmaxf(pm, __shfl_xor(pm, 32));

        if (!__all(pm - m_run <= THR)) {
            float mnew = fmaxf(m_run, pm);
            float corr = __builtin_amdgcn_exp2f(m_run - mnew);
            m_run = mnew;
            l_run *= corr;
            float cb[4];
#pragma unroll
            for (int r = 0; r < 4; ++r) cb[r] = __shfl(corr, lgrp * 4 + r);
#pragma unroll
            for (int n = 0; n < 4; n++)
#pragma unroll
                for (int r = 0; r < 4; r++) o_acc[n][r] *= cb[r];
        }

        float su = 0.f;
#pragma unroll
        for (int f = 0; f < 4; ++f)
#pragma unroll
            for (int r = 0; r < 4; ++r) {
                float pv = __builtin_amdgcn_exp2f(x[f][r] - m_run);
                x[f][r] = pv;
                su += pv;
            }
        l_run += su;

#pragma unroll
        for (int f = 0; f < 4; ++f) {
            unsigned int plo, phi;
            asm("v_cvt_pk_bf16_f32 %0, %1, %2"
                : "=v"(plo)
                : "v"(x[f][0]), "v"(x[f][1]));
            asm("v_cvt_pk_bf16_f32 %0, %1, %2"
                : "=v"(phi)
                : "v"(x[f][2]), "v"(x[f][3]));
            const int chunk = (f * 2 + (lgrp >> 1)) ^ (lrow & 7);
            uint2 pw;
            pw.x = plo;
            pw.y = phi;
            *reinterpret_cast<uint2*>(
                &Ps[w][lrow * 64 + chunk * 8 + (lgrp & 1) * 4]) = pw;
        }

        const unsigned short* vbuf = &Vs[cur][0];
        __builtin_amdgcn_s_setprio(1);
#pragma unroll
        for (int jc = 0; jc < 2; ++jc) {
            int pc = ((4 * jc + lgrp) ^ (lrow & 7)) * 8;
            bf16x8 pa =
                *reinterpret_cast<const bf16x8*>(&Ps[w][0] + lrow * 64 + pc);
#pragma unroll
            for (int n = 0; n < 4; n++) {
                int vrow = n * 16 + lrow;
                bf16x8 vb =
                    *reinterpret_cast<const bf16x8*>(vbuf + vrow * 64 + pc);
                o_acc[n] = MFMA16(pa, vb, o_acc[n]);
            }
        }
        __builtin_amdgcn_s_setprio(0);

        if (kv < 15) {
            asm volatile("s_waitcnt vmcnt(0)" ::: "memory");
            __syncthreads();
        }
    }

    float lt = l_run + __shfl_xor(l_run, 16);
    lt += __shfl_xor(lt, 32);
    float rl[4];
#pragma unroll
    for (int r = 0; r < 4; ++r) rl[r] = 1.0f / __shfl(lt, lgrp * 4 + r);

    // compact hi-only epilogue
#pragma unroll
    for (int n = 0; n < 4; n++) {
#pragma unroll
        for (int r = 0; r < 4; r++) {
            float val = o_acc[n][r] * rl[r];
            int ia = qt * 128 + w * 16 + lgrp * 4 + r;
            size_t m = (size_t)b * 1024 + ia;
            int col = h * 64 + n * 16 + lrow;
            A3[m * 1024 + col] = f2bf(val);
        }
    }
}

extern "C" void kernel_launch(void* const* d_in, const int* in_sizes, int n_in,
                              void* d_out, int out_size, void* d_ws,
                              size_t ws_size, hipStream_t stream) {
    const float* x = (const float*)d_in[0];
    const float* w_qkv = (const float*)d_in[1];
    const float* w_out = (const float*)d_in[2];
    const float* rel_bias = (const float*)d_in[3];
    float* out = (float*)d_out;

    char* ws = (char*)d_ws;
    size_t off = 0;
    auto alloc = [&](size_t bytes) {
        char* p = ws + off;
        off += (bytes + 255) & ~(size_t)255;
        return p;
    };
    unsigned short* A1h = (unsigned short*)alloc((size_t)4096 * 1024 * 2);
    unsigned short* W1h = (unsigned short*)alloc((size_t)3072 * 1024 * 2);
    unsigned short* Qb = (unsigned short*)alloc((size_t)64 * 1024 * 64 * 2);
    unsigned short* Kb = (unsigned short*)alloc((size_t)64 * 1024 * 64 * 2);
    unsigned short* Vb = (unsigned short*)alloc((size_t)64 * 1024 * 64 * 2);
    unsigned short* A3h = (unsigned short*)alloc((size_t)4096 * 1024 * 2);
    unsigned short* W3h = (unsigned short*)alloc((size_t)1024 * 1024 * 2);
    // V^T aliases A1h (8 MB each): A1h dead after gemm256_hi; transpose_v after.
    unsigned short* Vtg = A1h;

    hipLaunchKernelGGL(prep_all, dim3(2048), dim3(256), 0, stream, x, w_qkv,
                       w_out, A1h, W1h, W3h);
    hipLaunchKernelGGL(gemm256_hi, dim3(12, 16), dim3(512), 0, stream, A1h, W1h,
                       Qb, Kb, Vb);
    hipLaunchKernelGGL(transpose_v, dim3(16, 64), dim3(256), 0, stream, Vb, Vtg);
    hipLaunchKernelGGL(attn_kernel, dim3(8, 64), dim3(512), 0, stream, Qb, Kb,
                       Vtg, rel_bias, A3h);
    hipLaunchKernelGGL(gemm_out_v5, dim3(512), dim3(256), 0, stream, A3h, W3h,
                       out);
}

// Round 18
// 98.088 us; speedup vs baseline: 1.9822x; 1.0316x over previous
//
#include <hip/hip_runtime.h>
#include <hip/hip_bf16.h>

typedef short bf16x8 __attribute__((ext_vector_type(8)));
typedef float f32x4  __attribute__((ext_vector_type(4)));

typedef __attribute__((address_space(3))) void lds_t;
typedef __attribute__((address_space(1))) void gbl_t;

#define MFMA16(a,b,c) __builtin_amdgcn_mfma_f32_16x16x32_bf16((a),(b),(c),0,0,0)

__device__ __forceinline__ unsigned short f2bf(float f) {
    __hip_bfloat16 h = __float2bfloat16(f);
    return __builtin_bit_cast(unsigned short, h);
}
__device__ __forceinline__ float bf2f(unsigned short u) {
    __hip_bfloat16 h = __builtin_bit_cast(__hip_bfloat16, u);
    return __bfloat162float(h);
}

// ============================================================================
// Fused prep (R15, unchanged): x -> A1h, w_qkv (einops permute) -> W1h,
// w_out -> W3h.  All bf16 hi-only compact, float4-vectorized, grid-stride.
// ============================================================================
__global__ void prep_all(const float* __restrict__ x,
                         const float* __restrict__ w_qkv,
                         const float* __restrict__ w_out,
                         unsigned short* __restrict__ A1h,
                         unsigned short* __restrict__ W1h,
                         unsigned short* __restrict__ W3h) {
    const int NX = 4096 * 256, NW1 = 3072 * 256, NW3 = 1024 * 256;
    for (int idx = blockIdx.x * blockDim.x + threadIdx.x; idx < NX + NW1 + NW3;
         idx += gridDim.x * blockDim.x) {
        if (idx < NX) {
            int base = idx * 4;
            float4 v = *reinterpret_cast<const float4*>(x + base);
            ushort4 hi;
            hi.x = f2bf(v.x); hi.y = f2bf(v.y);
            hi.z = f2bf(v.z); hi.w = f2bf(v.w);
            *reinterpret_cast<ushort4*>(A1h + base) = hi;
        } else if (idx < NX + NW1) {
            int base = (idx - NX) * 4;
            int n = base >> 10, c = base & 1023;
            int d = n & 63, which = n >> 10, h = (n >> 6) & 15;
            int srow = d * 48 + which * 16 + h;
            float4 v =
                *reinterpret_cast<const float4*>(w_qkv + (size_t)srow * 1024 + c);
            ushort4 hi;
            hi.x = f2bf(v.x); hi.y = f2bf(v.y);
            hi.z = f2bf(v.z); hi.w = f2bf(v.w);
            *reinterpret_cast<ushort4*>(W1h + (size_t)n * 1024 + c) = hi;
        } else {
            int base = (idx - NX - NW1) * 4;
            float4 v = *reinterpret_cast<const float4*>(w_out + base);
            ushort4 hi;
            hi.x = f2bf(v.x); hi.y = f2bf(v.y);
            hi.z = f2bf(v.z); hi.w = f2bf(v.w);
            *reinterpret_cast<ushort4*>(W3h + base) = hi;
        }
    }
}

// ============================================================================
// QKV GEMM v6 (R17, unchanged — measured ~29us): BK=64, 16 steps, 64 MFMA/
// step/wave, 128KB 2-slot dbuf, XOR swizzle, grid (12,16), 8 waves.
// ============================================================================
__global__ __launch_bounds__(512, 1) void gemm256_hi(
    const unsigned short* __restrict__ A, const unsigned short* __restrict__ B,
    unsigned short* __restrict__ outQ, unsigned short* __restrict__ outK,
    unsigned short* __restrict__ outV) {
    __shared__ unsigned short lds[65536];
    const int tid = threadIdx.x;
    const int wid = tid >> 6, lane = tid & 63;
    const int lrow = lane & 15, lgrp = lane >> 4;
    const int wr = wid >> 2, wc = wid & 3;
    const int mtile = blockIdx.y * 256, ntile = blockIdx.x * 256;

    const int csw0 = (lgrp ^ (lrow & 7)) * 8;
    const int csw1 = ((4 | lgrp) ^ (lrow & 7)) * 8;
    const int arowb = (wr * 128 + lrow) * 64;
    const int browb = (wc * 64 + lrow) * 64;

    const int srow = tid >> 3;
    const int schunk = tid & 7;
    const int gchunk = schunk ^ (srow & 7);
    const unsigned short* Abase = A + (size_t)(mtile + srow) * 1024 + gchunk * 8;
    const unsigned short* Bbase = B + (size_t)(ntile + srow) * 1024 + gchunk * 8;
    const int sdst = srow * 64 + schunk * 8;

    f32x4 acc[8][4];
#pragma unroll
    for (int i = 0; i < 8; ++i)
#pragma unroll
        for (int j = 0; j < 4; ++j) {
            f32x4 z = {0.f, 0.f, 0.f, 0.f};
            acc[i][j] = z;
        }

#pragma unroll
    for (int e = 0; e < 4; ++e)
        __builtin_amdgcn_global_load_lds(
            (const gbl_t*)(Abase + (size_t)e * 64 * 1024),
            (lds_t*)(lds + e * 4096 + sdst), 16, 0, 0);
#pragma unroll
    for (int e = 0; e < 4; ++e)
        __builtin_amdgcn_global_load_lds(
            (const gbl_t*)(Bbase + (size_t)e * 64 * 1024),
            (lds_t*)(lds + 32768 + e * 4096 + sdst), 16, 0, 0);
    asm volatile("s_waitcnt vmcnt(0)" ::: "memory");
    __syncthreads();

    for (int s = 0; s < 16; ++s) {
        const int cur = s & 1;
        const unsigned short* abuf = lds + cur * 16384;
        const unsigned short* bbuf = lds + 32768 + cur * 16384;
        const int nx = cur ^ 1;
        const int kb = (s + 1) * 64;

        if (s < 15) {
#pragma unroll
            for (int e = 0; e < 4; ++e)
                __builtin_amdgcn_global_load_lds(
                    (const gbl_t*)(Abase + (size_t)e * 64 * 1024 + kb),
                    (lds_t*)(lds + nx * 16384 + e * 4096 + sdst), 16, 0, 0);
        }
        {
            bf16x8 af[8], bfv[4];
#pragma unroll
            for (int i = 0; i < 8; ++i)
                af[i] = *reinterpret_cast<const bf16x8*>(abuf + arowb + i * 1024 +
                                                         csw0);
#pragma unroll
            for (int j = 0; j < 4; ++j)
                bfv[j] = *reinterpret_cast<const bf16x8*>(bbuf + browb +
                                                          j * 1024 + csw0);
            __builtin_amdgcn_s_setprio(1);
#pragma unroll
            for (int i = 0; i < 8; ++i)
#pragma unroll
                for (int j = 0; j < 4; ++j)
                    acc[i][j] = MFMA16(af[i], bfv[j], acc[i][j]);
            __builtin_amdgcn_s_setprio(0);
        }
        if (s < 15) {
#pragma unroll
            for (int e = 0; e < 4; ++e)
                __builtin_amdgcn_global_load_lds(
                    (const gbl_t*)(Bbase + (size_t)e * 64 * 1024 + kb),
                    (lds_t*)(lds + 32768 + nx * 16384 + e * 4096 + sdst), 16, 0,
                    0);
        }
        {
            bf16x8 af[8], bfv[4];
#pragma unroll
            for (int i = 0; i < 8; ++i)
                af[i] = *reinterpret_cast<const bf16x8*>(abuf + arowb + i * 1024 +
                                                         csw1);
#pragma unroll
            for (int j = 0; j < 4; ++j)
                bfv[j] = *reinterpret_cast<const bf16x8*>(bbuf + browb +
                                                          j * 1024 + csw1);
            __builtin_amdgcn_s_setprio(1);
#pragma unroll
            for (int i = 0; i < 8; ++i)
#pragma unroll
                for (int j = 0; j < 4; ++j)
                    acc[i][j] = MFMA16(af[i], bfv[j], acc[i][j]);
            __builtin_amdgcn_s_setprio(0);
        }

        if (s < 15) {
            asm volatile("s_waitcnt vmcnt(0)" ::: "memory");
            __syncthreads();
        }
    }

#pragma unroll
    for (int i = 0; i < 8; ++i) {
#pragma unroll
        for (int j = 0; j < 4; ++j) {
#pragma unroll
            for (int r = 0; r < 4; ++r) {
                float v = acc[i][j][r];
                int m = mtile + wr * 128 + i * 16 + lgrp * 4 + r;
                int n = ntile + wc * 64 + j * 16 + lrow;
                int which = n >> 10;
                int hh = (n >> 6) & 15;
                int d = n & 63;
                int b = m >> 10, t = m & 1023;
                unsigned short* dstp =
                    (which == 0) ? outQ : ((which == 1) ? outK : outV);
                dstp[((size_t)((b << 4) + hh) * 1024 + t) * 64 + d] = f2bf(v);
            }
        }
    }
}

// ============================================================================
// Out-projection GEMM v5 (R16, unchanged — measured ~14us): BK=64, 16 steps,
// tile 64x128, 4 waves, 2-slot dbuf 48KB, XOR swizzle, XCD swizzle.
// ============================================================================
__global__ __launch_bounds__(256, 3) void gemm_out_v5(
    const unsigned short* __restrict__ A, const unsigned short* __restrict__ B,
    float* __restrict__ outF) {
    __shared__ unsigned short As[2][64 * 64];   // 16 KB
    __shared__ unsigned short Bs[2][128 * 64];  // 32 KB
    const int tid = threadIdx.x;
    const int wid = tid >> 6, lane = tid & 63;
    const int lrow = lane & 15, lgrp = lane >> 4;
    const int wr = wid >> 1, wc = wid & 1;
    const int h = blockIdx.x;
    const int xcd = h & 7, within = h >> 3;
    const int mtile = (xcd * 8 + (within & 7)) * 64;
    const int ntile = (within >> 3) * 128;

    const int srow = tid >> 3;
    const int schunk = (tid & 7) ^ (srow & 7);
    const unsigned short* Abase = A + (size_t)(mtile + srow) * 1024 + schunk * 8;
    const unsigned short* Bbase = B + (size_t)(ntile + srow) * 1024 + schunk * 8;

    const int csw0 = (lgrp ^ (lrow & 7)) * 8;
    const int csw1 = ((4 | lgrp) ^ (lrow & 7)) * 8;
    const int arow = wr * 32 + lrow;
    const int brow = wc * 64 + lrow;

    f32x4 acc[2][4];
#pragma unroll
    for (int i = 0; i < 2; ++i)
#pragma unroll
        for (int j = 0; j < 4; ++j) {
            f32x4 z = {0.f, 0.f, 0.f, 0.f};
            acc[i][j] = z;
        }

#pragma unroll
    for (int e = 0; e < 2; ++e)
        __builtin_amdgcn_global_load_lds(
            (const gbl_t*)(Abase + (size_t)e * 32 * 1024),
            (lds_t*)(&As[0][0] + e * 2048 + tid * 8), 16, 0, 0);
#pragma unroll
    for (int e = 0; e < 4; ++e)
        __builtin_amdgcn_global_load_lds(
            (const gbl_t*)(Bbase + (size_t)e * 32 * 1024),
            (lds_t*)(&Bs[0][0] + e * 2048 + tid * 8), 16, 0, 0);
    asm volatile("s_waitcnt vmcnt(0)" ::: "memory");
    __syncthreads();

    for (int s = 0; s < 16; ++s) {
        const int cur = s & 1;
        if (s < 15) {
            const int kb = (s + 1) * 64;
            const int nx = cur ^ 1;
#pragma unroll
            for (int e = 0; e < 2; ++e)
                __builtin_amdgcn_global_load_lds(
                    (const gbl_t*)(Abase + (size_t)e * 32 * 1024 + kb),
                    (lds_t*)(&As[nx][0] + e * 2048 + tid * 8), 16, 0, 0);
#pragma unroll
            for (int e = 0; e < 4; ++e)
                __builtin_amdgcn_global_load_lds(
                    (const gbl_t*)(Bbase + (size_t)e * 32 * 1024 + kb),
                    (lds_t*)(&Bs[nx][0] + e * 2048 + tid * 8), 16, 0, 0);
        }
        bf16x8 a0[2], a1[2], b0[4], b1[4];
#pragma unroll
        for (int i = 0; i < 2; ++i) {
            a0[i] = *reinterpret_cast<const bf16x8*>(&As[cur][0] +
                                                     (arow + i * 16) * 64 + csw0);
            a1[i] = *reinterpret_cast<const bf16x8*>(&As[cur][0] +
                                                     (arow + i * 16) * 64 + csw1);
        }
#pragma unroll
        for (int j = 0; j < 4; ++j) {
            b0[j] = *reinterpret_cast<const bf16x8*>(&Bs[cur][0] +
                                                     (brow + j * 16) * 64 + csw0);
            b1[j] = *reinterpret_cast<const bf16x8*>(&Bs[cur][0] +
                                                     (brow + j * 16) * 64 + csw1);
        }
        __builtin_amdgcn_s_setprio(1);
#pragma unroll
        for (int i = 0; i < 2; ++i)
#pragma unroll
            for (int j = 0; j < 4; ++j) {
                acc[i][j] = MFMA16(a0[i], b0[j], acc[i][j]);
                acc[i][j] = MFMA16(a1[i], b1[j], acc[i][j]);
            }
        __builtin_amdgcn_s_setprio(0);
        if (s < 15) {
            asm volatile("s_waitcnt vmcnt(0)" ::: "memory");
            __syncthreads();
        }
    }

#pragma unroll
    for (int i = 0; i < 2; ++i)
#pragma unroll
        for (int j = 0; j < 4; ++j)
#pragma unroll
            for (int r = 0; r < 4; ++r) {
                int m = mtile + wr * 32 + i * 16 + lgrp * 4 + r;
                int n = ntile + wc * 64 + j * 16 + lrow;
                outF[(size_t)m * 1024 + n] = acc[i][j][r];
            }
}

// V [bh][1024][64] -> V^T [bh][64][1024], LDS-tiled, coalesced both sides.
__global__ __launch_bounds__(256) void transpose_v(
    const unsigned short* __restrict__ Vb, unsigned short* __restrict__ Vtg) {
    __shared__ unsigned short L[64][72];
    const int tt = blockIdx.x, bh = blockIdx.y;
    const int tid = threadIdx.x;
#pragma unroll
    for (int e = 0; e < 2; ++e) {
        int chunk = e * 256 + tid;
        int r = chunk >> 3, c = (chunk & 7) * 8;
        uint4 v = *reinterpret_cast<const uint4*>(
            Vb + ((size_t)bh * 1024 + tt * 64 + r) * 64 + c);
        *reinterpret_cast<uint4*>(&L[r][c]) = v;
    }
    __syncthreads();
#pragma unroll
    for (int e = 0; e < 2; ++e) {
        int chunk = e * 256 + tid;
        int d = chunk >> 3, t0 = (chunk & 7) * 8;
        unsigned short tmp[8];
#pragma unroll
        for (int u = 0; u < 8; ++u) tmp[u] = L[t0 + u][d];
        *reinterpret_cast<uint4*>(Vtg + ((size_t)bh * 64 + d) * 1024 + tt * 64 +
                                  t0) = *reinterpret_cast<const uint4*>(tmp);
    }
}

// ============================================================================
// Flash attention (R16 structure) + R18 XCD-locality grid swap (T1).
// OLD grid (8,64): flat = qt + 8*bh -> XCD = qt%8 -> the 8 q-blocks sharing
// one bh's K/V land on 8 DIFFERENT XCDs (each XCD re-fetches K+V: FETCH 70MB
// vs 33MB compulsory).  NEW grid (64,8): bh = blockIdx.x, qt = blockIdx.y ->
// flat = bh + 64*qt -> XCD = bh%8: all 8 q-blocks of a bh on ONE XCD;
// per-XCD K/V footprint 8 bh x 256KB = 2MB < 4MB L2.
// ============================================================================
__global__ __launch_bounds__(512) void attn_kernel(
    const unsigned short* __restrict__ Qb, const unsigned short* __restrict__ Kb,
    const unsigned short* __restrict__ Vtg, const float* __restrict__ rel_bias,
    unsigned short* __restrict__ A3) {
    const int bh = blockIdx.x;  // 0..63  (XCD = bh%8)
    const int qt = blockIdx.y;  // 0..7 (128 q-rows each)
    const int b = bh >> 4, h = bh & 15;
    const int tid = threadIdx.x;
    const int w = tid >> 6, lane = tid & 63;  // w in 0..7
    const int lrow = lane & 15, lgrp = lane >> 4;
    const float LOG2E = 1.4426950408889634f;
    const float SCALE2 = 0.125f * 1.4426950408889634f;
    const float THR = 11.5f;  // ~8 nats in exp2 units

    __shared__ unsigned short Ks[2][64 * 64];  // 16 KB
    __shared__ unsigned short Vs[2][64 * 64];  // 16 KB
    __shared__ unsigned short Ps[8][16 * 64];  // 16 KB
    __shared__ float BiasF[1152];              // 4.5 KB, staged once

    const unsigned short* Ktile = Kb + (size_t)bh * 1024 * 64;
    const unsigned short* Vtile = Vtg + (size_t)bh * 64 * 1024;

    const unsigned short* Qp =
        Qb + ((size_t)bh * 1024 + qt * 128 + w * 16 + lrow) * 64;
    bf16x8 qa0 = *reinterpret_cast<const bf16x8*>(Qp + lgrp * 8);
    bf16x8 qa1 = *reinterpret_cast<const bf16x8*>(Qp + 32 + lgrp * 8);

    const int sr0 = w * 8 + (lane >> 3);
    const int sc_lo = lane & 7;

    float m_run = -3.0e38f;
    float l_run = 0.f;
    f32x4 o_acc[4];
#pragma unroll
    for (int n = 0; n < 4; n++) {
        f32x4 z = {0.f, 0.f, 0.f, 0.f};
        o_acc[n] = z;
    }

    const int bbase = lgrp * 4 + 127 - w * 16 - lrow;

    {
        {
            int r = sr0;
            int c = sc_lo ^ (r & 7);
            __builtin_amdgcn_global_load_lds(
                (const gbl_t*)(Ktile + (size_t)r * 64 + c * 8),
                (lds_t*)(&Ks[0][0] + w * 512), 16, 0, 0);
            __builtin_amdgcn_global_load_lds(
                (const gbl_t*)(Vtile + (size_t)r * 1024 + c * 8),
                (lds_t*)(&Vs[0][0] + w * 512), 16, 0, 0);
        }
        const int rbase = 896 - qt * 128;
        for (int t = tid; t < 1151; t += 512)
            BiasF[t] = rel_bias[(size_t)(t + rbase) * 16 + h] * LOG2E;
        asm volatile("s_waitcnt vmcnt(0)" ::: "memory");
        __syncthreads();
    }

    for (int kv = 0; kv < 16; ++kv) {
        const int cur = kv & 1;
        const int j0 = kv * 64;
        if (kv < 15) {
            const int j0n = (kv + 1) * 64;
            int r = sr0;
            int c = sc_lo ^ (r & 7);
            __builtin_amdgcn_global_load_lds(
                (const gbl_t*)(Ktile + (size_t)(j0n + r) * 64 + c * 8),
                (lds_t*)(&Ks[cur ^ 1][0] + w * 512), 16, 0, 0);
            __builtin_amdgcn_global_load_lds(
                (const gbl_t*)(Vtile + (size_t)r * 1024 + j0n + c * 8),
                (lds_t*)(&Vs[cur ^ 1][0] + w * 512), 16, 0, 0);
        }

        const unsigned short* kbuf = &Ks[cur][0];
        f32x4 s[4];
        __builtin_amdgcn_s_setprio(1);
#pragma unroll
        for (int f = 0; f < 4; ++f) {
            int krow = f * 16 + lrow;
            int sw0 = (lgrp ^ (lrow & 7)) * 8;
            int sw1 = ((4 | lgrp) ^ (lrow & 7)) * 8;
            bf16x8 kb0 = *reinterpret_cast<const bf16x8*>(kbuf + krow * 64 + sw0);
            bf16x8 kb1 = *reinterpret_cast<const bf16x8*>(kbuf + krow * 64 + sw1);
            f32x4 z = {0.f, 0.f, 0.f, 0.f};
            z = MFMA16(kb0, qa0, z);
            z = MFMA16(kb1, qa1, z);
            s[f] = z;
        }
        __builtin_amdgcn_s_setprio(0);

        float x[4][4];
        float pm = -3.0e38f;
#pragma unroll
        for (int f = 0; f < 4; ++f)
#pragma unroll
            for (int r = 0; r < 4; ++r) {
                float xv = s[f][r] * SCALE2 + BiasF[j0 + bbase + f * 16 + r];
                x[f][r] = xv;
                pm = fmaxf(pm, xv);
            }
        pm = fmaxf(pm, __shfl_xor(pm, 16));
        pm = fmaxf(pm, __shfl_xor(pm, 32));

        if (!__all(pm - m_run <= THR)) {
            float mnew = fmaxf(m_run, pm);
            float corr = __builtin_amdgcn_exp2f(m_run - mnew);
            m_run = mnew;
            l_run *= corr;
            float cb[4];
#pragma unroll
            for (int r = 0; r < 4; ++r) cb[r] = __shfl(corr, lgrp * 4 + r);
#pragma unroll
            for (int n = 0; n < 4; n++)
#pragma unroll
                for (int r = 0; r < 4; r++) o_acc[n][r] *= cb[r];
        }

        float su = 0.f;
#pragma unroll
        for (int f = 0; f < 4; ++f)
#pragma unroll
            for (int r = 0; r < 4; ++r) {
                float pv = __builtin_amdgcn_exp2f(x[f][r] - m_run);
                x[f][r] = pv;
                su += pv;
            }
        l_run += su;

#pragma unroll
        for (int f = 0; f < 4; ++f) {
            unsigned int plo, phi;
            asm("v_cvt_pk_bf16_f32 %0, %1, %2"
                : "=v"(plo)
                : "v"(x[f][0]), "v"(x[f][1]));
            asm("v_cvt_pk_bf16_f32 %0, %1, %2"
                : "=v"(phi)
                : "v"(x[f][2]), "v"(x[f][3]));
            const int chunk = (f * 2 + (lgrp >> 1)) ^ (lrow & 7);
            uint2 pw;
            pw.x = plo;
            pw.y = phi;
            *reinterpret_cast<uint2*>(
                &Ps[w][lrow * 64 + chunk * 8 + (lgrp & 1) * 4]) = pw;
        }

        const unsigned short* vbuf = &Vs[cur][0];
        __builtin_amdgcn_s_setprio(1);
#pragma unroll
        for (int jc = 0; jc < 2; ++jc) {
            int pc = ((4 * jc + lgrp) ^ (lrow & 7)) * 8;
            bf16x8 pa =
                *reinterpret_cast<const bf16x8*>(&Ps[w][0] + lrow * 64 + pc);
#pragma unroll
            for (int n = 0; n < 4; n++) {
                int vrow = n * 16 + lrow;
                bf16x8 vb =
                    *reinterpret_cast<const bf16x8*>(vbuf + vrow * 64 + pc);
                o_acc[n] = MFMA16(pa, vb, o_acc[n]);
            }
        }
        __builtin_amdgcn_s_setprio(0);

        if (kv < 15) {
            asm volatile("s_waitcnt vmcnt(0)" ::: "memory");
            __syncthreads();
        }
    }

    float lt = l_run + __shfl_xor(l_run, 16);
    lt += __shfl_xor(lt, 32);
    float rl[4];
#pragma unroll
    for (int r = 0; r < 4; ++r) rl[r] = 1.0f / __shfl(lt, lgrp * 4 + r);

    // compact hi-only epilogue
#pragma unroll
    for (int n = 0; n < 4; n++) {
#pragma unroll
        for (int r = 0; r < 4; r++) {
            float val = o_acc[n][r] * rl[r];
            int ia = qt * 128 + w * 16 + lgrp * 4 + r;
            size_t m = (size_t)b * 1024 + ia;
            int col = h * 64 + n * 16 + lrow;
            A3[m * 1024 + col] = f2bf(val);
        }
    }
}

extern "C" void kernel_launch(void* const* d_in, const int* in_sizes, int n_in,
                              void* d_out, int out_size, void* d_ws,
                              size_t ws_size, hipStream_t stream) {
    const float* x = (const float*)d_in[0];
    const float* w_qkv = (const float*)d_in[1];
    const float* w_out = (const float*)d_in[2];
    const float* rel_bias = (const float*)d_in[3];
    float* out = (float*)d_out;

    char* ws = (char*)d_ws;
    size_t off = 0;
    auto alloc = [&](size_t bytes) {
        char* p = ws + off;
        off += (bytes + 255) & ~(size_t)255;
        return p;
    };
    unsigned short* A1h = (unsigned short*)alloc((size_t)4096 * 1024 * 2);
    unsigned short* W1h = (unsigned short*)alloc((size_t)3072 * 1024 * 2);
    unsigned short* Qb = (unsigned short*)alloc((size_t)64 * 1024 * 64 * 2);
    unsigned short* Kb = (unsigned short*)alloc((size_t)64 * 1024 * 64 * 2);
    unsigned short* Vb = (unsigned short*)alloc((size_t)64 * 1024 * 64 * 2);
    unsigned short* A3h = (unsigned short*)alloc((size_t)4096 * 1024 * 2);
    unsigned short* W3h = (unsigned short*)alloc((size_t)1024 * 1024 * 2);
    // V^T aliases A1h (8 MB each): A1h dead after gemm256_hi; transpose_v after.
    unsigned short* Vtg = A1h;

    hipLaunchKernelGGL(prep_all, dim3(2048), dim3(256), 0, stream, x, w_qkv,
                       w_out, A1h, W1h, W3h);
    hipLaunchKernelGGL(gemm256_hi, dim3(12, 16), dim3(512), 0, stream, A1h, W1h,
                       Qb, Kb, Vb);
    hipLaunchKernelGGL(transpose_v, dim3(16, 64), dim3(256), 0, stream, Vb, Vtg);
    hipLaunchKernelGGL(attn_kernel, dim3(64, 8), dim3(512), 0, stream, Qb, Kb,
                       Vtg, rel_bias, A3h);
    hipLaunchKernelGGL(gemm_out_v5, dim3(512), dim3(256), 0, stream, A3h, W3h,
                       out);
}